// Round 6
// baseline (300.626 us; speedup 1.0000x reference)
//
#include <hip/hip_runtime.h>
#include <hip/hip_bf16.h>

// GCN 3-layer. Linearity: segsum(h[src]) @ W == segsum((h@W)[src]).
// R6: wave-per-node aggregation (4 edge-slots x 16 feature-lanes, shfl-xor
//     cross-slot reduce) -> zero intra-wave divergence in the gather loop.
// Pipeline:
//   CSR build (binned)              prep_w: Wt0/Wt1[n][k] bf16
//   bufA(bf16) = features @ Wt0 (MFMA);  bufB(bf16) = relu(agg128(bufA)+b0)
//   bufA(bf16) = bufB @ Wt1 (MFMA);      bufB(bf16) = relu(agg128(bufA)+b1)
//   bufC(bf16) = bufB @ W2 (vector);     out(f32)   = agg40(bufC)+b2

#define FEAT 128
#define BIN_SHIFT 8
#define MAX_BINS 512
#define SCAT_TILE 8192

typedef __attribute__((ext_vector_type(8))) short bf16x8_t;
typedef __attribute__((ext_vector_type(4))) float f32x4_t;

// ---------------- helpers ----------------

__device__ __forceinline__ void bf16x8_add(float* a, uint4 v) {
    a[0] += __uint_as_float(v.x << 16);
    a[1] += __uint_as_float(v.x & 0xffff0000u);
    a[2] += __uint_as_float(v.y << 16);
    a[3] += __uint_as_float(v.y & 0xffff0000u);
    a[4] += __uint_as_float(v.z << 16);
    a[5] += __uint_as_float(v.z & 0xffff0000u);
    a[6] += __uint_as_float(v.w << 16);
    a[7] += __uint_as_float(v.w & 0xffff0000u);
}

__device__ __forceinline__ unsigned pack_bf16(float a, float b) {
    union { __hip_bfloat162 h; unsigned u; } c;
    c.h.x = __float2bfloat16(a);
    c.h.y = __float2bfloat16(b);
    return c.u;
}

__device__ __forceinline__ unsigned short f2bf(float x) {
    union { __hip_bfloat16 h; unsigned short s; } c;
    c.h = __float2bfloat16(x);
    return c.s;
}

// ---------------- CSR build ----------------

__global__ __launch_bounds__(256) void bin_count(const int* __restrict__ dst,
                                                 int* __restrict__ bin_counts,
                                                 int n_edges, int nb) {
    __shared__ int hist[MAX_BINS];
    const int t = threadIdx.x;
    for (int i = t; i < nb; i += 256) hist[i] = 0;
    __syncthreads();
    const int n4 = n_edges >> 2;
    for (int i = blockIdx.x * 256 + t; i < n4; i += gridDim.x * 256) {
        int4 d = ((const int4*)dst)[i];
        atomicAdd(&hist[d.x >> BIN_SHIFT], 1);
        atomicAdd(&hist[d.y >> BIN_SHIFT], 1);
        atomicAdd(&hist[d.z >> BIN_SHIFT], 1);
        atomicAdd(&hist[d.w >> BIN_SHIFT], 1);
    }
    if (blockIdx.x == 0 && t < (n_edges & 3))
        atomicAdd(&hist[dst[n4 * 4 + t] >> BIN_SHIFT], 1);
    __syncthreads();
    for (int i = t; i < nb; i += 256) {
        int h = hist[i];
        if (h) atomicAdd(&bin_counts[i], h);
    }
}

__global__ __launch_bounds__(512) void bin_scan(const int* __restrict__ bin_counts,
                                                int* __restrict__ bin_offsets,
                                                int* __restrict__ bin_cursor,
                                                int* __restrict__ offsets,
                                                int nb, int n_nodes, int n_edges) {
    __shared__ int sc[512];
    const int t = threadIdx.x;
    const int v = (t < nb) ? bin_counts[t] : 0;
    sc[t] = v;
    __syncthreads();
    for (int off = 1; off < 512; off <<= 1) {
        int u = (t >= off) ? sc[t - off] : 0;
        __syncthreads();
        sc[t] += u;
        __syncthreads();
    }
    if (t <= nb) {
        int e = (t < nb) ? (sc[t] - v) : n_edges;
        bin_offsets[t] = e;
        if (t < nb) bin_cursor[t] = e;
    }
    if (t == 0) offsets[n_nodes] = n_edges;
}

__global__ __launch_bounds__(256) void bin_scatter(const int* __restrict__ src,
                                                   const int* __restrict__ dst,
                                                   int* __restrict__ bin_cursor,
                                                   int* __restrict__ ebuf,
                                                   int n_edges, int nb) {
    __shared__ int hist[MAX_BINS];
    __shared__ int cur[MAX_BINS];
    const int t = threadIdx.x;
    const int lo = blockIdx.x * SCAT_TILE;
    const int hi = min(lo + SCAT_TILE, n_edges);
    for (int i = t; i < nb; i += 256) hist[i] = 0;
    __syncthreads();
    for (int i = lo + t; i < hi; i += 256) atomicAdd(&hist[dst[i] >> BIN_SHIFT], 1);
    __syncthreads();
    for (int i = t; i < nb; i += 256) {
        int h = hist[i];
        cur[i] = h ? atomicAdd(&bin_cursor[i], h) : 0;
    }
    __syncthreads();
    for (int i = lo + t; i < hi; i += 256) {
        int d = dst[i];
        int b = d >> BIN_SHIFT;
        int pos = atomicAdd(&cur[b], 1);
        ebuf[pos] = ((d & 255) << 24) | src[i];
    }
}

__global__ __launch_bounds__(256) void csr_build(const int* __restrict__ ebuf,
                                                 const int* __restrict__ bin_offsets,
                                                 int* __restrict__ offsets,
                                                 int* __restrict__ csr,
                                                 int n_nodes) {
    __shared__ int cnt[256];
    __shared__ int sc[256];
    __shared__ int cur[256];
    const int b = blockIdx.x;
    const int t = threadIdx.x;
    const int lo = bin_offsets[b];
    const int hi = bin_offsets[b + 1];
    cnt[t] = 0;
    __syncthreads();
    for (int e = lo + t; e < hi; e += 256)
        atomicAdd(&cnt[((unsigned)ebuf[e]) >> 24], 1);
    __syncthreads();
    const int x = cnt[t];
    sc[t] = x;
    __syncthreads();
    for (int off = 1; off < 256; off <<= 1) {
        int u = (t >= off) ? sc[t - off] : 0;
        __syncthreads();
        sc[t] += u;
        __syncthreads();
    }
    const int start = lo + sc[t] - x;
    cur[t] = start;
    const int node = (b << BIN_SHIFT) + t;
    if (node < n_nodes) offsets[node] = start;
    __syncthreads();
    for (int e = lo + t; e < hi; e += 256) {
        int p = ebuf[e];
        int dl = ((unsigned)p) >> 24;
        int pos = atomicAdd(&cur[dl], 1);
        csr[pos] = p & 0x00FFFFFF;
    }
}

// ---------------- prep_w: Wt[n][k] (bf16) = W[k][n] (f32), 128x128 x2 ----------

__global__ __launch_bounds__(256) void prep_w(const float* __restrict__ W0,
                                              const float* __restrict__ W1,
                                              unsigned short* __restrict__ Wt0,
                                              unsigned short* __restrict__ Wt1) {
    int i = blockIdx.x * 256 + threadIdx.x;  // 0..32767
    const float* W = (i < 16384) ? W0 : W1;
    unsigned short* Wt = (i < 16384) ? Wt0 : Wt1;
    int ii = i & 16383;
    int k = ii >> 7, nn = ii & 127;
    Wt[nn * 128 + k] = f2bf(W[ii]);
}

// ------- agg128_wave: Y[n,128](bf16) = relu(sum_e X[csr[e],128](bf16) + bias) ----
// ONE WAVE PER NODE: 4 edge-slots x 16 feature-lanes; slot-strided edge loop
// (uniform trip count across the wave), unroll-4 (16 gather rows in flight),
// then shfl-xor(16,32) cross-slot reduce. Zero intra-wave divergence.

__global__ __launch_bounds__(256) void agg128_wave(const unsigned* __restrict__ X,
                                                   const int* __restrict__ offsets,
                                                   const int* __restrict__ csr_src,
                                                   const float* __restrict__ bias,
                                                   unsigned* __restrict__ Yb, int n) {
    const int t = threadIdx.x;
    const int wid = t >> 6;
    const int lane = t & 63;
    const int slot = lane >> 4;   // 0..3
    const int fl = lane & 15;     // uint4 index within row
    const int node = blockIdx.x * 4 + wid;
    if (node >= n) return;
    const int e0 = offsets[node];
    const int e1 = offsets[node + 1];
    const int cu = fl * 4;
    float acc[8] = {0.f, 0.f, 0.f, 0.f, 0.f, 0.f, 0.f, 0.f};
    int e = e0 + slot;
    for (; e + 12 < e1; e += 16) {
        int s0 = csr_src[e];
        int s1 = csr_src[e + 4];
        int s2 = csr_src[e + 8];
        int s3 = csr_src[e + 12];
        uint4 v0 = *(const uint4*)(X + (size_t)s0 * 64 + cu);
        uint4 v1 = *(const uint4*)(X + (size_t)s1 * 64 + cu);
        uint4 v2 = *(const uint4*)(X + (size_t)s2 * 64 + cu);
        uint4 v3 = *(const uint4*)(X + (size_t)s3 * 64 + cu);
        bf16x8_add(acc, v0);
        bf16x8_add(acc, v1);
        bf16x8_add(acc, v2);
        bf16x8_add(acc, v3);
    }
    for (; e < e1; e += 4) {
        int s0 = csr_src[e];
        uint4 v0 = *(const uint4*)(X + (size_t)s0 * 64 + cu);
        bf16x8_add(acc, v0);
    }
#pragma unroll
    for (int i = 0; i < 8; ++i) {
        acc[i] += __shfl_xor(acc[i], 16);
        acc[i] += __shfl_xor(acc[i], 32);
    }
    if (slot == 0) {
        float4 b0 = *(const float4*)(bias + fl * 8);
        float4 b1 = *(const float4*)(bias + fl * 8 + 4);
        acc[0] = fmaxf(acc[0] + b0.x, 0.f);
        acc[1] = fmaxf(acc[1] + b0.y, 0.f);
        acc[2] = fmaxf(acc[2] + b0.z, 0.f);
        acc[3] = fmaxf(acc[3] + b0.w, 0.f);
        acc[4] = fmaxf(acc[4] + b1.x, 0.f);
        acc[5] = fmaxf(acc[5] + b1.y, 0.f);
        acc[6] = fmaxf(acc[6] + b1.z, 0.f);
        acc[7] = fmaxf(acc[7] + b1.w, 0.f);
        *(uint4*)(Yb + (size_t)node * 64 + cu) =
            make_uint4(pack_bf16(acc[0], acc[1]), pack_bf16(acc[2], acc[3]),
                       pack_bf16(acc[4], acc[5]), pack_bf16(acc[6], acc[7]));
    }
}

// ------- agg40_wave: out[n,40](f32) = sum X[csr[e],40](bf16) + bias ----------
// One wave per node: 8 edge-slots x 8 lanes (5 of 8 carry a uint4).

__global__ __launch_bounds__(256) void agg40_wave(const unsigned* __restrict__ X,
                                                  const int* __restrict__ offsets,
                                                  const int* __restrict__ csr_src,
                                                  const float* __restrict__ bias,
                                                  float* __restrict__ Y, int n) {
    const int t = threadIdx.x;
    const int wid = t >> 6;
    const int lane = t & 63;
    const int slot = lane >> 3;   // 0..7
    const int fl = lane & 7;      // 0..7, active if <5
    const int node = blockIdx.x * 4 + wid;
    if (node >= n) return;
    const int e0 = offsets[node];
    const int e1 = offsets[node + 1];
    const bool active = fl < 5;
    const int cu = fl * 4;
    float acc[8] = {0.f, 0.f, 0.f, 0.f, 0.f, 0.f, 0.f, 0.f};
    int e = e0 + slot;
    for (; e + 8 < e1; e += 16) {
        int s0 = csr_src[e];
        int s1 = csr_src[e + 8];
        if (active) {
            uint4 v0 = *(const uint4*)(X + (size_t)s0 * 20 + cu);
            uint4 v1 = *(const uint4*)(X + (size_t)s1 * 20 + cu);
            bf16x8_add(acc, v0);
            bf16x8_add(acc, v1);
        }
    }
    for (; e < e1; e += 8) {
        int s0 = csr_src[e];
        if (active) {
            uint4 v0 = *(const uint4*)(X + (size_t)s0 * 20 + cu);
            bf16x8_add(acc, v0);
        }
    }
#pragma unroll
    for (int i = 0; i < 8; ++i) {
        acc[i] += __shfl_xor(acc[i], 8);
        acc[i] += __shfl_xor(acc[i], 16);
        acc[i] += __shfl_xor(acc[i], 32);
    }
    if (lane < 5) {  // slot==0 && fl<5
        float4 b0 = *(const float4*)(bias + fl * 8);
        float4 b1 = *(const float4*)(bias + fl * 8 + 4);
        float* yp = Y + (size_t)node * 40 + fl * 8;
        *(float4*)yp = make_float4(acc[0] + b0.x, acc[1] + b0.y,
                                   acc[2] + b0.z, acc[3] + b0.w);
        *(float4*)(yp + 4) = make_float4(acc[4] + b1.x, acc[5] + b1.y,
                                         acc[6] + b1.z, acc[7] + b1.w);
    }
}

// ------- mm128_mfma: C[N,128](bf16) = A[N,128] @ W[128,128], MFMA 16x16x32 -----

template <bool AF32>
__global__ __launch_bounds__(256) void mm128_mfma(const void* __restrict__ Av,
                                                  const unsigned* __restrict__ Wt,
                                                  unsigned* __restrict__ C, int n) {
    __shared__ __align__(16) unsigned char smem[128 * 272];  // 34 KB, W then C
    const int t = threadIdx.x;
    const int w = t >> 6;
    const int l = t & 63;
    const int rl = l & 15;
    const int g = l >> 4;
    const int row0 = blockIdx.x * 128;

    for (int i = t; i < 2048; i += 256) {
        int nn = i >> 4, j = i & 15;
        *(uint4*)(smem + nn * 272 + j * 16) = *(const uint4*)(Wt + nn * 64 + j * 4);
    }

    bf16x8_t a[2][4];
#pragma unroll
    for (int rt = 0; rt < 2; ++rt) {
        const int row = row0 + w * 32 + rt * 16 + rl;
        const bool ok = row < n;
#pragma unroll
        for (int kc = 0; kc < 4; ++kc) {
            union { uint4 u; bf16x8_t h; } pk;
            pk.u = make_uint4(0, 0, 0, 0);
            if (AF32) {
                if (ok) {
                    const float* ap = (const float*)Av + (size_t)row * 128 + kc * 32 + g * 8;
                    float4 lo = *(const float4*)ap;
                    float4 hi = *(const float4*)(ap + 4);
                    pk.u = make_uint4(pack_bf16(lo.x, lo.y), pack_bf16(lo.z, lo.w),
                                      pack_bf16(hi.x, hi.y), pack_bf16(hi.z, hi.w));
                }
            } else {
                if (ok)
                    pk.u = *(const uint4*)((const unsigned*)Av + (size_t)row * 64 + kc * 16 + g * 4);
            }
            a[rt][kc] = pk.h;
        }
    }
    __syncthreads();

    f32x4_t acc[2][8];
#pragma unroll
    for (int rt = 0; rt < 2; ++rt)
#pragma unroll
        for (int ct = 0; ct < 8; ++ct)
            acc[rt][ct] = (f32x4_t){0.f, 0.f, 0.f, 0.f};

#pragma unroll
    for (int ct = 0; ct < 8; ++ct) {
#pragma unroll
        for (int kc = 0; kc < 4; ++kc) {
            bf16x8_t b = *(const bf16x8_t*)(smem + (ct * 16 + rl) * 272 + kc * 64 + g * 16);
            acc[0][ct] = __builtin_amdgcn_mfma_f32_16x16x32_bf16(a[0][kc], b, acc[0][ct], 0, 0, 0);
            acc[1][ct] = __builtin_amdgcn_mfma_f32_16x16x32_bf16(a[1][kc], b, acc[1][ct], 0, 0, 0);
        }
    }
    __syncthreads();

#pragma unroll
    for (int rt = 0; rt < 2; ++rt)
#pragma unroll
        for (int ct = 0; ct < 8; ++ct)
#pragma unroll
            for (int r = 0; r < 4; ++r) {
                int lr = w * 32 + rt * 16 + g * 4 + r;
                int col = ct * 16 + rl;
                *(unsigned short*)(smem + lr * 272 + col * 2) = f2bf(acc[rt][ct][r]);
            }
    __syncthreads();

    for (int i = t; i < 2048; i += 256) {
        int r = i >> 4, j = i & 15;
        int row = row0 + r;
        if (row < n)
            *(uint4*)(C + (size_t)row * 64 + j * 4) = *(const uint4*)(smem + r * 272 + j * 16);
    }
}

// ---------------- mm40: C[N,40](bf16) = A[N,128](bf16) @ W[128,40](f32) --------

__global__ __launch_bounds__(256) void mm40_kernel(const unsigned* __restrict__ Ab,
                                                   const float* __restrict__ W,
                                                   unsigned* __restrict__ C, int n) {
    __shared__ float Wl[128][40];
    __shared__ __align__(16) float Al[32][132];
    __shared__ __align__(16) float Cl[32][40];
    const int t = threadIdx.x;
    const int row0 = blockIdx.x * 32;

    for (int i = t; i < 128 * 40; i += 256) Wl[i / 40][i % 40] = W[i];
    for (int i = t; i < 512; i += 256) {
        int r = i >> 4, j = i & 15;
        int row = row0 + r;
        uint4 v = make_uint4(0, 0, 0, 0);
        if (row < n) v = *(const uint4*)(Ab + (size_t)row * 64 + j * 4);
        float* d = &Al[r][j * 8];
        d[0] = __uint_as_float(v.x << 16); d[1] = __uint_as_float(v.x & 0xffff0000u);
        d[2] = __uint_as_float(v.y << 16); d[3] = __uint_as_float(v.y & 0xffff0000u);
        d[4] = __uint_as_float(v.z << 16); d[5] = __uint_as_float(v.z & 0xffff0000u);
        d[6] = __uint_as_float(v.w << 16); d[7] = __uint_as_float(v.w & 0xffff0000u);
    }
    __syncthreads();

    const int rl = t >> 3;
    const int c0 = (t & 7) * 5;
    float acc[5] = {0.f, 0.f, 0.f, 0.f, 0.f};
    for (int k = 0; k < 128; ++k) {
        float a = Al[rl][k];
#pragma unroll
        for (int j = 0; j < 5; ++j) acc[j] += a * Wl[k][c0 + j];
    }
#pragma unroll
    for (int j = 0; j < 5; ++j) Cl[rl][c0 + j] = acc[j];
    __syncthreads();

    for (int i = t; i < 160; i += 256) {
        int r = i / 5, q = i % 5;
        int row = row0 + r;
        if (row >= n) continue;
        const float* s = &Cl[r][q * 8];
        uint4 o = make_uint4(pack_bf16(s[0], s[1]), pack_bf16(s[2], s[3]),
                             pack_bf16(s[4], s[5]), pack_bf16(s[6], s[7]));
        *(uint4*)(C + (size_t)row * 20 + q * 4) = o;
    }
}

// ---------------- launch ----------------

extern "C" void kernel_launch(void* const* d_in, const int* in_sizes, int n_in,
                              void* d_out, int out_size, void* d_ws, size_t ws_size,
                              hipStream_t stream) {
    const float* features = (const float*)d_in[0];
    const int* src = (const int*)d_in[1];
    const int* dst = (const int*)d_in[2];
    const float* W0 = (const float*)d_in[3];
    const float* b0 = (const float*)d_in[4];
    const float* W1 = (const float*)d_in[5];
    const float* b1 = (const float*)d_in[6];
    const float* W2 = (const float*)d_in[7];
    const float* b2 = (const float*)d_in[8];
    float* out = (float*)d_out;

    const int n_nodes = in_sizes[0] / FEAT;
    const int n_edges = in_sizes[1];
    const int nb = (n_nodes + 255) >> BIN_SHIFT;

    char* p = (char*)d_ws;
    auto alloc = [&](size_t bytes) {
        char* q = p;
        p += (bytes + 255) & ~(size_t)255;
        return q;
    };
    unsigned* bufA  = (unsigned*)alloc((size_t)n_nodes * FEAT * 2);  // bf16 [N,128]
    unsigned* bufB  = (unsigned*)alloc((size_t)n_nodes * FEAT * 2);  // bf16 [N,128]
    int* offsets    = (int*)alloc((size_t)(n_nodes + 1) * 4);
    int* csr        = (int*)alloc((size_t)n_edges * 4);
    int* ebuf       = (int*)alloc((size_t)n_edges * 4);
    int* bin_counts = (int*)alloc(MAX_BINS * 4);
    int* bin_offs   = (int*)alloc((MAX_BINS + 1) * 4);
    int* bin_cursor = (int*)alloc(MAX_BINS * 4);
    unsigned short* Wt0 = (unsigned short*)alloc(16384 * 2);
    unsigned short* Wt1 = (unsigned short*)alloc(16384 * 2);
    unsigned* bufC  = bufA;  // alias: bf16 [N,40] fits in bufA's region

    // weight transpose (independent of CSR chain)
    prep_w<<<128, 256, 0, stream>>>(W0, W1, Wt0, Wt1);

    // CSR build (binned)
    hipMemsetAsync(bin_counts, 0, MAX_BINS * 4, stream);
    bin_count<<<256, 256, 0, stream>>>(dst, bin_counts, n_edges, nb);
    bin_scan<<<1, 512, 0, stream>>>(bin_counts, bin_offs, bin_cursor, offsets,
                                    nb, n_nodes, n_edges);
    bin_scatter<<<(n_edges + SCAT_TILE - 1) / SCAT_TILE, 256, 0, stream>>>(
        src, dst, bin_cursor, ebuf, n_edges, nb);
    csr_build<<<nb, 256, 0, stream>>>(ebuf, bin_offs, offsets, csr, n_nodes);

    const int mmf_grid = (n_nodes + 127) / 128;
    const int mm40_grid = (n_nodes + 31) / 32;
    const int aggw_grid = (n_nodes + 3) / 4;

    // layer 0
    mm128_mfma<true><<<mmf_grid, 256, 0, stream>>>(features, (const unsigned*)Wt0, bufA, n_nodes);
    agg128_wave<<<aggw_grid, 256, 0, stream>>>(bufA, offsets, csr, b0, bufB, n_nodes);
    // layer 1
    mm128_mfma<false><<<mmf_grid, 256, 0, stream>>>(bufB, (const unsigned*)Wt1, bufA, n_nodes);
    agg128_wave<<<aggw_grid, 256, 0, stream>>>(bufA, offsets, csr, b1, bufB, n_nodes);
    // layer 2: matmul-first (128->40), then aggregate + bias
    mm40_kernel<<<mm40_grid, 256, 0, stream>>>(bufB, W2, bufC, n_nodes);
    agg40_wave<<<aggw_grid, 256, 0, stream>>>(bufC, offsets, csr, b2, out, n_nodes);
}

// Round 7
// 282.537 us; speedup vs baseline: 1.0640x; 1.0640x over previous
//
#include <hip/hip_runtime.h>
#include <hip/hip_bf16.h>

// GCN 3-layer. Linearity: segsum(h[src]) @ W == segsum((h@W)[src]).
// R7: revert agg to R5 group-per-node (R6 wave-per-node regressed);
//     FUSE agg+matmul per layer (agg result -> LDS -> MFMA/vector mm),
//     removing the 51.2 MB global round-trip between agg and mm, x2.
// Pipeline:
//   CSR build (binned)   prep_w: Wt0/Wt1[n][k] bf16
//   bufA = features @ Wt0                       (mm128_mfma)
//   bufB = relu(agg(bufA)+b0) @ Wt1             (fused128: agg->LDS->MFMA)
//   bufC = relu(agg(bufB)+b1) @ W2              (fused40:  agg->LDS->vector mm)
//   out  = agg40(bufC) + b2                     (agg40)

#define FEAT 128
#define BIN_SHIFT 8
#define MAX_BINS 512
#define SCAT_TILE 8192

typedef __attribute__((ext_vector_type(8))) short bf16x8_t;
typedef __attribute__((ext_vector_type(4))) float f32x4_t;

// ---------------- helpers ----------------

__device__ __forceinline__ void bf16x8_add(float* a, uint4 v) {
    a[0] += __uint_as_float(v.x << 16);
    a[1] += __uint_as_float(v.x & 0xffff0000u);
    a[2] += __uint_as_float(v.y << 16);
    a[3] += __uint_as_float(v.y & 0xffff0000u);
    a[4] += __uint_as_float(v.z << 16);
    a[5] += __uint_as_float(v.z & 0xffff0000u);
    a[6] += __uint_as_float(v.w << 16);
    a[7] += __uint_as_float(v.w & 0xffff0000u);
}

__device__ __forceinline__ unsigned pack_bf16(float a, float b) {
    union { __hip_bfloat162 h; unsigned u; } c;
    c.h.x = __float2bfloat16(a);
    c.h.y = __float2bfloat16(b);
    return c.u;
}

__device__ __forceinline__ unsigned short f2bf(float x) {
    union { __hip_bfloat16 h; unsigned short s; } c;
    c.h = __float2bfloat16(x);
    return c.s;
}

// ---------------- CSR build ----------------

__global__ __launch_bounds__(256) void bin_count(const int* __restrict__ dst,
                                                 int* __restrict__ bin_counts,
                                                 int n_edges, int nb) {
    __shared__ int hist[MAX_BINS];
    const int t = threadIdx.x;
    for (int i = t; i < nb; i += 256) hist[i] = 0;
    __syncthreads();
    const int n4 = n_edges >> 2;
    for (int i = blockIdx.x * 256 + t; i < n4; i += gridDim.x * 256) {
        int4 d = ((const int4*)dst)[i];
        atomicAdd(&hist[d.x >> BIN_SHIFT], 1);
        atomicAdd(&hist[d.y >> BIN_SHIFT], 1);
        atomicAdd(&hist[d.z >> BIN_SHIFT], 1);
        atomicAdd(&hist[d.w >> BIN_SHIFT], 1);
    }
    if (blockIdx.x == 0 && t < (n_edges & 3))
        atomicAdd(&hist[dst[n4 * 4 + t] >> BIN_SHIFT], 1);
    __syncthreads();
    for (int i = t; i < nb; i += 256) {
        int h = hist[i];
        if (h) atomicAdd(&bin_counts[i], h);
    }
}

__global__ __launch_bounds__(512) void bin_scan(const int* __restrict__ bin_counts,
                                                int* __restrict__ bin_offsets,
                                                int* __restrict__ bin_cursor,
                                                int* __restrict__ offsets,
                                                int nb, int n_nodes, int n_edges) {
    __shared__ int sc[512];
    const int t = threadIdx.x;
    const int v = (t < nb) ? bin_counts[t] : 0;
    sc[t] = v;
    __syncthreads();
    for (int off = 1; off < 512; off <<= 1) {
        int u = (t >= off) ? sc[t - off] : 0;
        __syncthreads();
        sc[t] += u;
        __syncthreads();
    }
    if (t <= nb) {
        int e = (t < nb) ? (sc[t] - v) : n_edges;
        bin_offsets[t] = e;
        if (t < nb) bin_cursor[t] = e;
    }
    if (t == 0) offsets[n_nodes] = n_edges;
}

__global__ __launch_bounds__(256) void bin_scatter(const int* __restrict__ src,
                                                   const int* __restrict__ dst,
                                                   int* __restrict__ bin_cursor,
                                                   int* __restrict__ ebuf,
                                                   int n_edges, int nb) {
    __shared__ int hist[MAX_BINS];
    __shared__ int cur[MAX_BINS];
    const int t = threadIdx.x;
    const int lo = blockIdx.x * SCAT_TILE;
    const int hi = min(lo + SCAT_TILE, n_edges);
    for (int i = t; i < nb; i += 256) hist[i] = 0;
    __syncthreads();
    for (int i = lo + t; i < hi; i += 256) atomicAdd(&hist[dst[i] >> BIN_SHIFT], 1);
    __syncthreads();
    for (int i = t; i < nb; i += 256) {
        int h = hist[i];
        cur[i] = h ? atomicAdd(&bin_cursor[i], h) : 0;
    }
    __syncthreads();
    for (int i = lo + t; i < hi; i += 256) {
        int d = dst[i];
        int b = d >> BIN_SHIFT;
        int pos = atomicAdd(&cur[b], 1);
        ebuf[pos] = ((d & 255) << 24) | src[i];
    }
}

__global__ __launch_bounds__(256) void csr_build(const int* __restrict__ ebuf,
                                                 const int* __restrict__ bin_offsets,
                                                 int* __restrict__ offsets,
                                                 int* __restrict__ csr,
                                                 int n_nodes) {
    __shared__ int cnt[256];
    __shared__ int sc[256];
    __shared__ int cur[256];
    const int b = blockIdx.x;
    const int t = threadIdx.x;
    const int lo = bin_offsets[b];
    const int hi = bin_offsets[b + 1];
    cnt[t] = 0;
    __syncthreads();
    for (int e = lo + t; e < hi; e += 256)
        atomicAdd(&cnt[((unsigned)ebuf[e]) >> 24], 1);
    __syncthreads();
    const int x = cnt[t];
    sc[t] = x;
    __syncthreads();
    for (int off = 1; off < 256; off <<= 1) {
        int u = (t >= off) ? sc[t - off] : 0;
        __syncthreads();
        sc[t] += u;
        __syncthreads();
    }
    const int start = lo + sc[t] - x;
    cur[t] = start;
    const int node = (b << BIN_SHIFT) + t;
    if (node < n_nodes) offsets[node] = start;
    __syncthreads();
    for (int e = lo + t; e < hi; e += 256) {
        int p = ebuf[e];
        int dl = ((unsigned)p) >> 24;
        int pos = atomicAdd(&cur[dl], 1);
        csr[pos] = p & 0x00FFFFFF;
    }
}

// ---------------- prep_w: Wt[n][k] (bf16) = W[k][n] (f32), 128x128 x2 ----------

__global__ __launch_bounds__(256) void prep_w(const float* __restrict__ W0,
                                              const float* __restrict__ W1,
                                              unsigned short* __restrict__ Wt0,
                                              unsigned short* __restrict__ Wt1) {
    int i = blockIdx.x * 256 + threadIdx.x;  // 0..32767
    const float* W = (i < 16384) ? W0 : W1;
    unsigned short* Wt = (i < 16384) ? Wt0 : Wt1;
    int ii = i & 16383;
    int k = ii >> 7, nn = ii & 127;
    Wt[nn * 128 + k] = f2bf(W[ii]);
}

// ------- mm128_mfma: C[N,128](bf16) = A[N,128](f32) @ Wt, MFMA 16x16x32 -----
// (layer-0 only: A = features, fp32)

__global__ __launch_bounds__(256) void mm128_mfma(const float* __restrict__ A,
                                                  const unsigned* __restrict__ Wt,
                                                  unsigned* __restrict__ C, int n) {
    __shared__ __align__(16) unsigned char smem[128 * 272];  // W then C bounce
    const int t = threadIdx.x;
    const int w = t >> 6;
    const int l = t & 63;
    const int rl = l & 15;
    const int g = l >> 4;
    const int row0 = blockIdx.x * 128;

    for (int i = t; i < 2048; i += 256) {
        int nn = i >> 4, j = i & 15;
        *(uint4*)(smem + nn * 272 + j * 16) = *(const uint4*)(Wt + nn * 64 + j * 4);
    }

    bf16x8_t a[2][4];
#pragma unroll
    for (int rt = 0; rt < 2; ++rt) {
        const int row = row0 + w * 32 + rt * 16 + rl;
        const bool ok = row < n;
#pragma unroll
        for (int kc = 0; kc < 4; ++kc) {
            union { uint4 u; bf16x8_t h; } pk;
            pk.u = make_uint4(0, 0, 0, 0);
            if (ok) {
                const float* ap = A + (size_t)row * 128 + kc * 32 + g * 8;
                float4 lo = *(const float4*)ap;
                float4 hi = *(const float4*)(ap + 4);
                pk.u = make_uint4(pack_bf16(lo.x, lo.y), pack_bf16(lo.z, lo.w),
                                  pack_bf16(hi.x, hi.y), pack_bf16(hi.z, hi.w));
            }
            a[rt][kc] = pk.h;
        }
    }
    __syncthreads();

    f32x4_t acc[2][8];
#pragma unroll
    for (int rt = 0; rt < 2; ++rt)
#pragma unroll
        for (int ct = 0; ct < 8; ++ct)
            acc[rt][ct] = (f32x4_t){0.f, 0.f, 0.f, 0.f};

#pragma unroll
    for (int ct = 0; ct < 8; ++ct) {
#pragma unroll
        for (int kc = 0; kc < 4; ++kc) {
            bf16x8_t b = *(const bf16x8_t*)(smem + (ct * 16 + rl) * 272 + kc * 64 + g * 16);
            acc[0][ct] = __builtin_amdgcn_mfma_f32_16x16x32_bf16(a[0][kc], b, acc[0][ct], 0, 0, 0);
            acc[1][ct] = __builtin_amdgcn_mfma_f32_16x16x32_bf16(a[1][kc], b, acc[1][ct], 0, 0, 0);
        }
    }
    __syncthreads();

#pragma unroll
    for (int rt = 0; rt < 2; ++rt)
#pragma unroll
        for (int ct = 0; ct < 8; ++ct)
#pragma unroll
            for (int r = 0; r < 4; ++r) {
                int lr = w * 32 + rt * 16 + g * 4 + r;
                int col = ct * 16 + rl;
                *(unsigned short*)(smem + lr * 272 + col * 2) = f2bf(acc[rt][ct][r]);
            }
    __syncthreads();

    for (int i = t; i < 2048; i += 256) {
        int r = i >> 4, j = i & 15;
        int row = row0 + r;
        if (row < n)
            *(uint4*)(C + (size_t)row * 64 + j * 4) = *(const uint4*)(smem + r * 272 + j * 16);
    }
}

// ------- fused128: C[N,128](bf16) = relu(agg(X)+bias) @ Wt ------------------
// Phase 1: agg 64 nodes -> LDS bf16 (R5 group-per-node shape: 16 groups x 16
// lanes, 4 sequential nodes per group). Phase 2: MFMA, W staged in 32-k tiles.

__global__ __launch_bounds__(256) void fused128(const unsigned* __restrict__ X,
                                                const int* __restrict__ offsets,
                                                const int* __restrict__ csr_src,
                                                const float* __restrict__ bias,
                                                const unsigned* __restrict__ Wt,
                                                unsigned* __restrict__ C, int n) {
    __shared__ __align__(16) unsigned char Alds[64 * 272];   // agg result / C bounce
    __shared__ __align__(16) unsigned char Wlds[128 * 80];   // W k-tile
    const int t = threadIdx.x;
    const int row0 = blockIdx.x * 64;

    // ---- phase 1: aggregate 64 nodes into Alds (bf16, relu(agg+bias)) ----
    {
        const int gi = t >> 4;
        const int fl = t & 15;
        const int cu = fl * 4;
        for (int nn = 0; nn < 4; ++nn) {
            const int lr = gi * 4 + nn;
            const int node = row0 + lr;
            if (node >= n) continue;
            const int e0 = offsets[node];
            const int e1 = offsets[node + 1];
            float acc[8] = {0.f, 0.f, 0.f, 0.f, 0.f, 0.f, 0.f, 0.f};
            int e = e0;
            for (; e + 3 < e1; e += 4) {
                int s0 = csr_src[e];
                int s1 = csr_src[e + 1];
                int s2 = csr_src[e + 2];
                int s3 = csr_src[e + 3];
                uint4 v0 = *(const uint4*)(X + (size_t)s0 * 64 + cu);
                uint4 v1 = *(const uint4*)(X + (size_t)s1 * 64 + cu);
                uint4 v2 = *(const uint4*)(X + (size_t)s2 * 64 + cu);
                uint4 v3 = *(const uint4*)(X + (size_t)s3 * 64 + cu);
                bf16x8_add(acc, v0);
                bf16x8_add(acc, v1);
                bf16x8_add(acc, v2);
                bf16x8_add(acc, v3);
            }
            for (; e < e1; ++e) {
                int s0 = csr_src[e];
                uint4 v0 = *(const uint4*)(X + (size_t)s0 * 64 + cu);
                bf16x8_add(acc, v0);
            }
            float4 b0 = *(const float4*)(bias + fl * 8);
            float4 b1 = *(const float4*)(bias + fl * 8 + 4);
            acc[0] = fmaxf(acc[0] + b0.x, 0.f);
            acc[1] = fmaxf(acc[1] + b0.y, 0.f);
            acc[2] = fmaxf(acc[2] + b0.z, 0.f);
            acc[3] = fmaxf(acc[3] + b0.w, 0.f);
            acc[4] = fmaxf(acc[4] + b1.x, 0.f);
            acc[5] = fmaxf(acc[5] + b1.y, 0.f);
            acc[6] = fmaxf(acc[6] + b1.z, 0.f);
            acc[7] = fmaxf(acc[7] + b1.w, 0.f);
            *(uint4*)(Alds + lr * 272 + fl * 16) =
                make_uint4(pack_bf16(acc[0], acc[1]), pack_bf16(acc[2], acc[3]),
                           pack_bf16(acc[4], acc[5]), pack_bf16(acc[6], acc[7]));
        }
    }
    __syncthreads();

    // ---- phase 2: [64,128] @ W via MFMA; 4 waves x 16 rows ----
    const int w = t >> 6;
    const int l = t & 63;
    const int rl = l & 15;
    const int g = l >> 4;

    f32x4_t acc[8];
#pragma unroll
    for (int ct = 0; ct < 8; ++ct) acc[ct] = (f32x4_t){0.f, 0.f, 0.f, 0.f};

    for (int kt = 0; kt < 4; ++kt) {
        // stage W k-tile: cols(n) 0..127, k = kt*32..+32, pitch 80B
        for (int i = t; i < 512; i += 256) {
            int nn = i >> 2, j = i & 3;
            *(uint4*)(Wlds + nn * 80 + j * 16) = *(const uint4*)(Wt + nn * 64 + kt * 16 + j * 4);
        }
        __syncthreads();
        bf16x8_t a = *(const bf16x8_t*)(Alds + (w * 16 + rl) * 272 + kt * 64 + g * 16);
#pragma unroll
        for (int ct = 0; ct < 8; ++ct) {
            bf16x8_t b = *(const bf16x8_t*)(Wlds + (ct * 16 + rl) * 80 + g * 16);
            acc[ct] = __builtin_amdgcn_mfma_f32_16x16x32_bf16(a, b, acc[ct], 0, 0, 0);
        }
        __syncthreads();
    }

    // C -> Alds (bf16), then coalesced out
#pragma unroll
    for (int ct = 0; ct < 8; ++ct)
#pragma unroll
        for (int r = 0; r < 4; ++r)
            *(unsigned short*)(Alds + (w * 16 + g * 4 + r) * 272 + (ct * 16 + rl) * 2) =
                f2bf(acc[ct][r]);
    __syncthreads();

    for (int i = t; i < 1024; i += 256) {
        int r = i >> 4, j = i & 15;
        int row = row0 + r;
        if (row < n)
            *(uint4*)(C + (size_t)row * 64 + j * 4) = *(const uint4*)(Alds + r * 272 + j * 16);
    }
}

// ------- fused40: C[N,40](bf16) = relu(agg(X)+bias) @ W2[128,40](f32) --------

__global__ __launch_bounds__(256) void fused40(const unsigned* __restrict__ X,
                                               const int* __restrict__ offsets,
                                               const int* __restrict__ csr_src,
                                               const float* __restrict__ bias,
                                               const float* __restrict__ W2,
                                               unsigned* __restrict__ C, int n) {
    __shared__ __align__(16) unsigned char Alds[64 * 272];
    __shared__ float Wf[128 * 40];
    const int t = threadIdx.x;
    const int row0 = blockIdx.x * 64;

    // stage W2 (independent of phase-1 LDS region)
    for (int i = t; i < 5120; i += 256) Wf[i] = W2[i];

    // ---- phase 1: aggregate 64 nodes into Alds (bf16, relu(agg+bias)) ----
    {
        const int gi = t >> 4;
        const int fl = t & 15;
        const int cu = fl * 4;
        for (int nn = 0; nn < 4; ++nn) {
            const int lr = gi * 4 + nn;
            const int node = row0 + lr;
            if (node >= n) continue;
            const int e0 = offsets[node];
            const int e1 = offsets[node + 1];
            float acc[8] = {0.f, 0.f, 0.f, 0.f, 0.f, 0.f, 0.f, 0.f};
            int e = e0;
            for (; e + 3 < e1; e += 4) {
                int s0 = csr_src[e];
                int s1 = csr_src[e + 1];
                int s2 = csr_src[e + 2];
                int s3 = csr_src[e + 3];
                uint4 v0 = *(const uint4*)(X + (size_t)s0 * 64 + cu);
                uint4 v1 = *(const uint4*)(X + (size_t)s1 * 64 + cu);
                uint4 v2 = *(const uint4*)(X + (size_t)s2 * 64 + cu);
                uint4 v3 = *(const uint4*)(X + (size_t)s3 * 64 + cu);
                bf16x8_add(acc, v0);
                bf16x8_add(acc, v1);
                bf16x8_add(acc, v2);
                bf16x8_add(acc, v3);
            }
            for (; e < e1; ++e) {
                int s0 = csr_src[e];
                uint4 v0 = *(const uint4*)(X + (size_t)s0 * 64 + cu);
                bf16x8_add(acc, v0);
            }
            float4 b0 = *(const float4*)(bias + fl * 8);
            float4 b1 = *(const float4*)(bias + fl * 8 + 4);
            acc[0] = fmaxf(acc[0] + b0.x, 0.f);
            acc[1] = fmaxf(acc[1] + b0.y, 0.f);
            acc[2] = fmaxf(acc[2] + b0.z, 0.f);
            acc[3] = fmaxf(acc[3] + b0.w, 0.f);
            acc[4] = fmaxf(acc[4] + b1.x, 0.f);
            acc[5] = fmaxf(acc[5] + b1.y, 0.f);
            acc[6] = fmaxf(acc[6] + b1.z, 0.f);
            acc[7] = fmaxf(acc[7] + b1.w, 0.f);
            *(uint4*)(Alds + lr * 272 + fl * 16) =
                make_uint4(pack_bf16(acc[0], acc[1]), pack_bf16(acc[2], acc[3]),
                           pack_bf16(acc[4], acc[5]), pack_bf16(acc[6], acc[7]));
        }
    }
    __syncthreads();

    // ---- phase 2: [64,128] @ W2 -> [64,40], 8 thr/row x 5 cols, 2 row-passes ----
    const int rbase = t >> 3;          // 0..31
    const int c0 = (t & 7) * 5;
    float accA[5] = {0.f, 0.f, 0.f, 0.f, 0.f};
    float accB[5] = {0.f, 0.f, 0.f, 0.f, 0.f};
#pragma unroll 1
    for (int k = 0; k < 128; ++k) {
        float a0 = __uint_as_float(
            (unsigned)(*(const unsigned short*)(Alds + rbase * 272 + k * 2)) << 16);
        float a1 = __uint_as_float(
            (unsigned)(*(const unsigned short*)(Alds + (rbase + 32) * 272 + k * 2)) << 16);
        const float* wr = &Wf[k * 40 + c0];
#pragma unroll
        for (int j = 0; j < 5; ++j) {
            float wv = wr[j];
            accA[j] += a0 * wv;
            accB[j] += a1 * wv;
        }
    }
    __syncthreads();  // all Alds reads done; reuse as f32 bounce (pitch 68 u32)

    float* bounce = (float*)Alds;
#pragma unroll
    for (int j = 0; j < 5; ++j) {
        bounce[rbase * 68 + c0 + j] = accA[j];
        bounce[(rbase + 32) * 68 + c0 + j] = accB[j];
    }
    __syncthreads();

    for (int i = t; i < 1280; i += 256) {  // 64 rows x 20 u32
        int r = i / 20, j = i % 20;
        int row = row0 + r;
        if (row < n)
            C[(size_t)row * 20 + j] =
                pack_bf16(bounce[r * 68 + j * 2], bounce[r * 68 + j * 2 + 1]);
    }
}

// ------- agg40: out[n,40](f32) = sum X[csr[e],40](bf16) + bias ----------
// 8 lanes per node, lanes 0..4 each own a uint4; 32 nodes per block.

__global__ __launch_bounds__(256) void agg40_bf16(const unsigned* __restrict__ X,
                                                  const int* __restrict__ offsets,
                                                  const int* __restrict__ csr_src,
                                                  const float* __restrict__ bias,
                                                  float* __restrict__ Y, int n) {
    const int t = threadIdx.x;
    const int g = t >> 3;
    const int lane = t & 7;
    const int node = blockIdx.x * 32 + g;
    if (node >= n) return;
    const int e0 = offsets[node];
    const int e1 = offsets[node + 1];
    const bool active = lane < 5;
    const int cu = lane * 4;
    float acc[8] = {0.f, 0.f, 0.f, 0.f, 0.f, 0.f, 0.f, 0.f};
    int e = e0;
    for (; e + 3 < e1; e += 4) {
        int s0 = csr_src[e];
        int s1 = csr_src[e + 1];
        int s2 = csr_src[e + 2];
        int s3 = csr_src[e + 3];
        if (active) {
            uint4 v0 = *(const uint4*)(X + (size_t)s0 * 20 + cu);
            uint4 v1 = *(const uint4*)(X + (size_t)s1 * 20 + cu);
            uint4 v2 = *(const uint4*)(X + (size_t)s2 * 20 + cu);
            uint4 v3 = *(const uint4*)(X + (size_t)s3 * 20 + cu);
            bf16x8_add(acc, v0);
            bf16x8_add(acc, v1);
            bf16x8_add(acc, v2);
            bf16x8_add(acc, v3);
        }
    }
    for (; e < e1; ++e) {
        int s0 = csr_src[e];
        if (active) {
            uint4 v0 = *(const uint4*)(X + (size_t)s0 * 20 + cu);
            bf16x8_add(acc, v0);
        }
    }
    if (active) {
        float4 b0 = *(const float4*)(bias + lane * 8);
        float4 b1 = *(const float4*)(bias + lane * 8 + 4);
        float* yp = Y + (size_t)node * 40 + lane * 8;
        *(float4*)yp = make_float4(acc[0] + b0.x, acc[1] + b0.y,
                                   acc[2] + b0.z, acc[3] + b0.w);
        *(float4*)(yp + 4) = make_float4(acc[4] + b1.x, acc[5] + b1.y,
                                         acc[6] + b1.z, acc[7] + b1.w);
    }
}

// ---------------- launch ----------------

extern "C" void kernel_launch(void* const* d_in, const int* in_sizes, int n_in,
                              void* d_out, int out_size, void* d_ws, size_t ws_size,
                              hipStream_t stream) {
    const float* features = (const float*)d_in[0];
    const int* src = (const int*)d_in[1];
    const int* dst = (const int*)d_in[2];
    const float* W0 = (const float*)d_in[3];
    const float* b0 = (const float*)d_in[4];
    const float* W1 = (const float*)d_in[5];
    const float* b1 = (const float*)d_in[6];
    const float* W2 = (const float*)d_in[7];
    const float* b2 = (const float*)d_in[8];
    float* out = (float*)d_out;

    const int n_nodes = in_sizes[0] / FEAT;
    const int n_edges = in_sizes[1];
    const int nb = (n_nodes + 255) >> BIN_SHIFT;

    char* p = (char*)d_ws;
    auto alloc = [&](size_t bytes) {
        char* q = p;
        p += (bytes + 255) & ~(size_t)255;
        return q;
    };
    unsigned* bufA  = (unsigned*)alloc((size_t)n_nodes * FEAT * 2);  // bf16 [N,128]
    unsigned* bufB  = (unsigned*)alloc((size_t)n_nodes * FEAT * 2);  // bf16 [N,128]
    int* offsets    = (int*)alloc((size_t)(n_nodes + 1) * 4);
    int* csr        = (int*)alloc((size_t)n_edges * 4);
    int* ebuf       = (int*)alloc((size_t)n_edges * 4);
    int* bin_counts = (int*)alloc(MAX_BINS * 4);
    int* bin_offs   = (int*)alloc((MAX_BINS + 1) * 4);
    int* bin_cursor = (int*)alloc(MAX_BINS * 4);
    unsigned short* Wt0 = (unsigned short*)alloc(16384 * 2);
    unsigned short* Wt1 = (unsigned short*)alloc(16384 * 2);
    unsigned* bufC  = bufA;  // alias: bf16 [N,40] fits in bufA's region (bufA dead)

    // weight transpose (independent of CSR chain)
    prep_w<<<128, 256, 0, stream>>>(W0, W1, Wt0, Wt1);

    // CSR build (binned)
    hipMemsetAsync(bin_counts, 0, MAX_BINS * 4, stream);
    bin_count<<<256, 256, 0, stream>>>(dst, bin_counts, n_edges, nb);
    bin_scan<<<1, 512, 0, stream>>>(bin_counts, bin_offs, bin_cursor, offsets,
                                    nb, n_nodes, n_edges);
    bin_scatter<<<(n_edges + SCAT_TILE - 1) / SCAT_TILE, 256, 0, stream>>>(
        src, dst, bin_cursor, ebuf, n_edges, nb);
    csr_build<<<nb, 256, 0, stream>>>(ebuf, bin_offs, offsets, csr, n_nodes);

    const int mmf_grid = (n_nodes + 127) / 128;
    const int fuse_grid = (n_nodes + 63) / 64;
    const int agg40_grid = (n_nodes + 31) / 32;

    // layer 0 matmul
    mm128_mfma<<<mmf_grid, 256, 0, stream>>>(features, (const unsigned*)Wt0, bufA, n_nodes);
    // layer 0 agg + layer 1 matmul (fused)
    fused128<<<fuse_grid, 256, 0, stream>>>(bufA, offsets, csr, b0,
                                            (const unsigned*)Wt1, bufB, n_nodes);
    // layer 1 agg + layer 2 matmul (fused)
    fused40<<<fuse_grid, 256, 0, stream>>>(bufB, offsets, csr, b1, W2, bufC, n_nodes);
    // layer 2 agg + bias
    agg40_bf16<<<agg40_grid, 256, 0, stream>>>(bufC, offsets, csr, b2, out, n_nodes);
}

// Round 8
// 266.377 us; speedup vs baseline: 1.1286x; 1.0607x over previous
//
#include <hip/hip_runtime.h>
#include <hip/hip_bf16.h>

// GCN 3-layer. Linearity: segsum(h[src]) @ W == segsum((h@W)[src]).
// R8: fused40 phase-2 rebuilt as MFMA (R7's scalar-LDS vector mm was 93us with
//     187K bank conflicts + 33% occupancy). W2 pre-transposed to bf16 [48][128]
//     (zero-padded rows 40..47). Agg phases byte-identical to R7.
// Pipeline:
//   CSR build (binned)   prep_w: Wt0/Wt1[128][128] + W2t[48][128] bf16
//   bufA = features @ Wt0                       (mm128_mfma)
//   bufB = relu(agg(bufA)+b0) @ Wt1             (fused128: agg->LDS->MFMA)
//   bufC = relu(agg(bufB)+b1) @ W2t             (fused40:  agg->LDS->MFMA)
//   out  = agg40(bufC) + b2                     (agg40)

#define FEAT 128
#define BIN_SHIFT 8
#define MAX_BINS 512
#define SCAT_TILE 8192

typedef __attribute__((ext_vector_type(8))) short bf16x8_t;
typedef __attribute__((ext_vector_type(4))) float f32x4_t;

// ---------------- helpers ----------------

__device__ __forceinline__ void bf16x8_add(float* a, uint4 v) {
    a[0] += __uint_as_float(v.x << 16);
    a[1] += __uint_as_float(v.x & 0xffff0000u);
    a[2] += __uint_as_float(v.y << 16);
    a[3] += __uint_as_float(v.y & 0xffff0000u);
    a[4] += __uint_as_float(v.z << 16);
    a[5] += __uint_as_float(v.z & 0xffff0000u);
    a[6] += __uint_as_float(v.w << 16);
    a[7] += __uint_as_float(v.w & 0xffff0000u);
}

__device__ __forceinline__ unsigned pack_bf16(float a, float b) {
    union { __hip_bfloat162 h; unsigned u; } c;
    c.h.x = __float2bfloat16(a);
    c.h.y = __float2bfloat16(b);
    return c.u;
}

__device__ __forceinline__ unsigned short f2bf(float x) {
    union { __hip_bfloat16 h; unsigned short s; } c;
    c.h = __float2bfloat16(x);
    return c.s;
}

// ---------------- CSR build ----------------

__global__ __launch_bounds__(256) void bin_count(const int* __restrict__ dst,
                                                 int* __restrict__ bin_counts,
                                                 int n_edges, int nb) {
    __shared__ int hist[MAX_BINS];
    const int t = threadIdx.x;
    for (int i = t; i < nb; i += 256) hist[i] = 0;
    __syncthreads();
    const int n4 = n_edges >> 2;
    for (int i = blockIdx.x * 256 + t; i < n4; i += gridDim.x * 256) {
        int4 d = ((const int4*)dst)[i];
        atomicAdd(&hist[d.x >> BIN_SHIFT], 1);
        atomicAdd(&hist[d.y >> BIN_SHIFT], 1);
        atomicAdd(&hist[d.z >> BIN_SHIFT], 1);
        atomicAdd(&hist[d.w >> BIN_SHIFT], 1);
    }
    if (blockIdx.x == 0 && t < (n_edges & 3))
        atomicAdd(&hist[dst[n4 * 4 + t] >> BIN_SHIFT], 1);
    __syncthreads();
    for (int i = t; i < nb; i += 256) {
        int h = hist[i];
        if (h) atomicAdd(&bin_counts[i], h);
    }
}

__global__ __launch_bounds__(512) void bin_scan(const int* __restrict__ bin_counts,
                                                int* __restrict__ bin_offsets,
                                                int* __restrict__ bin_cursor,
                                                int* __restrict__ offsets,
                                                int nb, int n_nodes, int n_edges) {
    __shared__ int sc[512];
    const int t = threadIdx.x;
    const int v = (t < nb) ? bin_counts[t] : 0;
    sc[t] = v;
    __syncthreads();
    for (int off = 1; off < 512; off <<= 1) {
        int u = (t >= off) ? sc[t - off] : 0;
        __syncthreads();
        sc[t] += u;
        __syncthreads();
    }
    if (t <= nb) {
        int e = (t < nb) ? (sc[t] - v) : n_edges;
        bin_offsets[t] = e;
        if (t < nb) bin_cursor[t] = e;
    }
    if (t == 0) offsets[n_nodes] = n_edges;
}

__global__ __launch_bounds__(256) void bin_scatter(const int* __restrict__ src,
                                                   const int* __restrict__ dst,
                                                   int* __restrict__ bin_cursor,
                                                   int* __restrict__ ebuf,
                                                   int n_edges, int nb) {
    __shared__ int hist[MAX_BINS];
    __shared__ int cur[MAX_BINS];
    const int t = threadIdx.x;
    const int lo = blockIdx.x * SCAT_TILE;
    const int hi = min(lo + SCAT_TILE, n_edges);
    for (int i = t; i < nb; i += 256) hist[i] = 0;
    __syncthreads();
    for (int i = lo + t; i < hi; i += 256) atomicAdd(&hist[dst[i] >> BIN_SHIFT], 1);
    __syncthreads();
    for (int i = t; i < nb; i += 256) {
        int h = hist[i];
        cur[i] = h ? atomicAdd(&bin_cursor[i], h) : 0;
    }
    __syncthreads();
    for (int i = lo + t; i < hi; i += 256) {
        int d = dst[i];
        int b = d >> BIN_SHIFT;
        int pos = atomicAdd(&cur[b], 1);
        ebuf[pos] = ((d & 255) << 24) | src[i];
    }
}

__global__ __launch_bounds__(256) void csr_build(const int* __restrict__ ebuf,
                                                 const int* __restrict__ bin_offsets,
                                                 int* __restrict__ offsets,
                                                 int* __restrict__ csr,
                                                 int n_nodes) {
    __shared__ int cnt[256];
    __shared__ int sc[256];
    __shared__ int cur[256];
    const int b = blockIdx.x;
    const int t = threadIdx.x;
    const int lo = bin_offsets[b];
    const int hi = bin_offsets[b + 1];
    cnt[t] = 0;
    __syncthreads();
    for (int e = lo + t; e < hi; e += 256)
        atomicAdd(&cnt[((unsigned)ebuf[e]) >> 24], 1);
    __syncthreads();
    const int x = cnt[t];
    sc[t] = x;
    __syncthreads();
    for (int off = 1; off < 256; off <<= 1) {
        int u = (t >= off) ? sc[t - off] : 0;
        __syncthreads();
        sc[t] += u;
        __syncthreads();
    }
    const int start = lo + sc[t] - x;
    cur[t] = start;
    const int node = (b << BIN_SHIFT) + t;
    if (node < n_nodes) offsets[node] = start;
    __syncthreads();
    for (int e = lo + t; e < hi; e += 256) {
        int p = ebuf[e];
        int dl = ((unsigned)p) >> 24;
        int pos = atomicAdd(&cur[dl], 1);
        csr[pos] = p & 0x00FFFFFF;
    }
}

// -------- prep_w: Wt0/Wt1[n][k] bf16 from W0/W1[k][n] f32; W2t[48][128] bf16 ----

__global__ __launch_bounds__(256) void prep_w(const float* __restrict__ W0,
                                              const float* __restrict__ W1,
                                              const float* __restrict__ W2,
                                              unsigned short* __restrict__ Wt0,
                                              unsigned short* __restrict__ Wt1,
                                              unsigned short* __restrict__ W2t) {
    int i = blockIdx.x * 256 + threadIdx.x;  // 0..38911
    if (i < 32768) {
        const float* W = (i < 16384) ? W0 : W1;
        unsigned short* Wt = (i < 16384) ? Wt0 : Wt1;
        int ii = i & 16383;
        int k = ii >> 7, nn = ii & 127;
        Wt[nn * 128 + k] = f2bf(W[ii]);
    } else if (i < 32768 + 48 * 128) {
        int ii = i - 32768;           // nn*128 + k
        int nn = ii >> 7, k = ii & 127;
        W2t[ii] = (nn < 40) ? f2bf(W2[k * 40 + nn]) : (unsigned short)0;
    }
}

// ------- mm128_mfma: C[N,128](bf16) = A[N,128](f32) @ Wt, MFMA 16x16x32 -----
// (layer-0 only: A = features, fp32)

__global__ __launch_bounds__(256) void mm128_mfma(const float* __restrict__ A,
                                                  const unsigned* __restrict__ Wt,
                                                  unsigned* __restrict__ C, int n) {
    __shared__ __align__(16) unsigned char smem[128 * 272];  // W then C bounce
    const int t = threadIdx.x;
    const int w = t >> 6;
    const int l = t & 63;
    const int rl = l & 15;
    const int g = l >> 4;
    const int row0 = blockIdx.x * 128;

    for (int i = t; i < 2048; i += 256) {
        int nn = i >> 4, j = i & 15;
        *(uint4*)(smem + nn * 272 + j * 16) = *(const uint4*)(Wt + nn * 64 + j * 4);
    }

    bf16x8_t a[2][4];
#pragma unroll
    for (int rt = 0; rt < 2; ++rt) {
        const int row = row0 + w * 32 + rt * 16 + rl;
        const bool ok = row < n;
#pragma unroll
        for (int kc = 0; kc < 4; ++kc) {
            union { uint4 u; bf16x8_t h; } pk;
            pk.u = make_uint4(0, 0, 0, 0);
            if (ok) {
                const float* ap = A + (size_t)row * 128 + kc * 32 + g * 8;
                float4 lo = *(const float4*)ap;
                float4 hi = *(const float4*)(ap + 4);
                pk.u = make_uint4(pack_bf16(lo.x, lo.y), pack_bf16(lo.z, lo.w),
                                  pack_bf16(hi.x, hi.y), pack_bf16(hi.z, hi.w));
            }
            a[rt][kc] = pk.h;
        }
    }
    __syncthreads();

    f32x4_t acc[2][8];
#pragma unroll
    for (int rt = 0; rt < 2; ++rt)
#pragma unroll
        for (int ct = 0; ct < 8; ++ct)
            acc[rt][ct] = (f32x4_t){0.f, 0.f, 0.f, 0.f};

#pragma unroll
    for (int ct = 0; ct < 8; ++ct) {
#pragma unroll
        for (int kc = 0; kc < 4; ++kc) {
            bf16x8_t b = *(const bf16x8_t*)(smem + (ct * 16 + rl) * 272 + kc * 64 + g * 16);
            acc[0][ct] = __builtin_amdgcn_mfma_f32_16x16x32_bf16(a[0][kc], b, acc[0][ct], 0, 0, 0);
            acc[1][ct] = __builtin_amdgcn_mfma_f32_16x16x32_bf16(a[1][kc], b, acc[1][ct], 0, 0, 0);
        }
    }
    __syncthreads();

#pragma unroll
    for (int rt = 0; rt < 2; ++rt)
#pragma unroll
        for (int ct = 0; ct < 8; ++ct)
#pragma unroll
            for (int r = 0; r < 4; ++r) {
                int lr = w * 32 + rt * 16 + g * 4 + r;
                int col = ct * 16 + rl;
                *(unsigned short*)(smem + lr * 272 + col * 2) = f2bf(acc[rt][ct][r]);
            }
    __syncthreads();

    for (int i = t; i < 2048; i += 256) {
        int r = i >> 4, j = i & 15;
        int row = row0 + r;
        if (row < n)
            *(uint4*)(C + (size_t)row * 64 + j * 4) = *(const uint4*)(smem + r * 272 + j * 16);
    }
}

// ------- fused128: C[N,128](bf16) = relu(agg(X)+bias) @ Wt ------------------
// Phase 1: agg 64 nodes -> LDS bf16 (16 groups x 16 lanes, 4 nodes per group).
// Phase 2: MFMA, W staged in 32-k tiles.

__global__ __launch_bounds__(256) void fused128(const unsigned* __restrict__ X,
                                                const int* __restrict__ offsets,
                                                const int* __restrict__ csr_src,
                                                const float* __restrict__ bias,
                                                const unsigned* __restrict__ Wt,
                                                unsigned* __restrict__ C, int n) {
    __shared__ __align__(16) unsigned char Alds[64 * 272];   // agg result / C bounce
    __shared__ __align__(16) unsigned char Wlds[128 * 80];   // W k-tile
    const int t = threadIdx.x;
    const int row0 = blockIdx.x * 64;

    // ---- phase 1: aggregate 64 nodes into Alds (bf16, relu(agg+bias)) ----
    {
        const int gi = t >> 4;
        const int fl = t & 15;
        const int cu = fl * 4;
        for (int nn = 0; nn < 4; ++nn) {
            const int lr = gi * 4 + nn;
            const int node = row0 + lr;
            if (node >= n) continue;
            const int e0 = offsets[node];
            const int e1 = offsets[node + 1];
            float acc[8] = {0.f, 0.f, 0.f, 0.f, 0.f, 0.f, 0.f, 0.f};
            int e = e0;
            for (; e + 3 < e1; e += 4) {
                int s0 = csr_src[e];
                int s1 = csr_src[e + 1];
                int s2 = csr_src[e + 2];
                int s3 = csr_src[e + 3];
                uint4 v0 = *(const uint4*)(X + (size_t)s0 * 64 + cu);
                uint4 v1 = *(const uint4*)(X + (size_t)s1 * 64 + cu);
                uint4 v2 = *(const uint4*)(X + (size_t)s2 * 64 + cu);
                uint4 v3 = *(const uint4*)(X + (size_t)s3 * 64 + cu);
                bf16x8_add(acc, v0);
                bf16x8_add(acc, v1);
                bf16x8_add(acc, v2);
                bf16x8_add(acc, v3);
            }
            for (; e < e1; ++e) {
                int s0 = csr_src[e];
                uint4 v0 = *(const uint4*)(X + (size_t)s0 * 64 + cu);
                bf16x8_add(acc, v0);
            }
            float4 b0 = *(const float4*)(bias + fl * 8);
            float4 b1 = *(const float4*)(bias + fl * 8 + 4);
            acc[0] = fmaxf(acc[0] + b0.x, 0.f);
            acc[1] = fmaxf(acc[1] + b0.y, 0.f);
            acc[2] = fmaxf(acc[2] + b0.z, 0.f);
            acc[3] = fmaxf(acc[3] + b0.w, 0.f);
            acc[4] = fmaxf(acc[4] + b1.x, 0.f);
            acc[5] = fmaxf(acc[5] + b1.y, 0.f);
            acc[6] = fmaxf(acc[6] + b1.z, 0.f);
            acc[7] = fmaxf(acc[7] + b1.w, 0.f);
            *(uint4*)(Alds + lr * 272 + fl * 16) =
                make_uint4(pack_bf16(acc[0], acc[1]), pack_bf16(acc[2], acc[3]),
                           pack_bf16(acc[4], acc[5]), pack_bf16(acc[6], acc[7]));
        }
    }
    __syncthreads();

    // ---- phase 2: [64,128] @ W via MFMA; 4 waves x 16 rows ----
    const int w = t >> 6;
    const int l = t & 63;
    const int rl = l & 15;
    const int g = l >> 4;

    f32x4_t acc[8];
#pragma unroll
    for (int ct = 0; ct < 8; ++ct) acc[ct] = (f32x4_t){0.f, 0.f, 0.f, 0.f};

    for (int kt = 0; kt < 4; ++kt) {
        for (int i = t; i < 512; i += 256) {
            int nn = i >> 2, j = i & 3;
            *(uint4*)(Wlds + nn * 80 + j * 16) = *(const uint4*)(Wt + nn * 64 + kt * 16 + j * 4);
        }
        __syncthreads();
        bf16x8_t a = *(const bf16x8_t*)(Alds + (w * 16 + rl) * 272 + kt * 64 + g * 16);
#pragma unroll
        for (int ct = 0; ct < 8; ++ct) {
            bf16x8_t b = *(const bf16x8_t*)(Wlds + (ct * 16 + rl) * 80 + g * 16);
            acc[ct] = __builtin_amdgcn_mfma_f32_16x16x32_bf16(a, b, acc[ct], 0, 0, 0);
        }
        __syncthreads();
    }

    // C -> Alds (bf16), then coalesced out
#pragma unroll
    for (int ct = 0; ct < 8; ++ct)
#pragma unroll
        for (int r = 0; r < 4; ++r)
            *(unsigned short*)(Alds + (w * 16 + g * 4 + r) * 272 + (ct * 16 + rl) * 2) =
                f2bf(acc[ct][r]);
    __syncthreads();

    for (int i = t; i < 1024; i += 256) {
        int r = i >> 4, j = i & 15;
        int row = row0 + r;
        if (row < n)
            *(uint4*)(C + (size_t)row * 64 + j * 4) = *(const uint4*)(Alds + r * 272 + j * 16);
    }
}

// ------- fused40: C[N,40](bf16) = relu(agg(X)+bias) @ W2t, MFMA --------------
// Phase 1 identical to fused128. Phase 2: W2t[48][128] bf16 (rows 40..47 zero),
// 3 col-tiles x 4 k-chunks = 12 MFMA/wave. f32 bounce -> packed bf16 out.

__global__ __launch_bounds__(256) void fused40(const unsigned* __restrict__ X,
                                               const int* __restrict__ offsets,
                                               const int* __restrict__ csr_src,
                                               const float* __restrict__ bias,
                                               const unsigned* __restrict__ W2t,
                                               unsigned* __restrict__ C, int n) {
    __shared__ __align__(16) unsigned char Alds[64 * 272];   // agg result / bounce
    __shared__ __align__(16) unsigned char Wlds[48 * 272];   // W2t staged
    const int t = threadIdx.x;
    const int row0 = blockIdx.x * 64;

    // stage W2t (48 rows x 16 uint4)
    for (int i = t; i < 768; i += 256) {
        int nn = i >> 4, j = i & 15;
        *(uint4*)(Wlds + nn * 272 + j * 16) = *(const uint4*)(W2t + nn * 64 + j * 4);
    }

    // ---- phase 1: aggregate 64 nodes into Alds (bf16, relu(agg+bias)) ----
    {
        const int gi = t >> 4;
        const int fl = t & 15;
        const int cu = fl * 4;
        for (int nn = 0; nn < 4; ++nn) {
            const int lr = gi * 4 + nn;
            const int node = row0 + lr;
            if (node >= n) continue;
            const int e0 = offsets[node];
            const int e1 = offsets[node + 1];
            float acc[8] = {0.f, 0.f, 0.f, 0.f, 0.f, 0.f, 0.f, 0.f};
            int e = e0;
            for (; e + 3 < e1; e += 4) {
                int s0 = csr_src[e];
                int s1 = csr_src[e + 1];
                int s2 = csr_src[e + 2];
                int s3 = csr_src[e + 3];
                uint4 v0 = *(const uint4*)(X + (size_t)s0 * 64 + cu);
                uint4 v1 = *(const uint4*)(X + (size_t)s1 * 64 + cu);
                uint4 v2 = *(const uint4*)(X + (size_t)s2 * 64 + cu);
                uint4 v3 = *(const uint4*)(X + (size_t)s3 * 64 + cu);
                bf16x8_add(acc, v0);
                bf16x8_add(acc, v1);
                bf16x8_add(acc, v2);
                bf16x8_add(acc, v3);
            }
            for (; e < e1; ++e) {
                int s0 = csr_src[e];
                uint4 v0 = *(const uint4*)(X + (size_t)s0 * 64 + cu);
                bf16x8_add(acc, v0);
            }
            float4 b0 = *(const float4*)(bias + fl * 8);
            float4 b1 = *(const float4*)(bias + fl * 8 + 4);
            acc[0] = fmaxf(acc[0] + b0.x, 0.f);
            acc[1] = fmaxf(acc[1] + b0.y, 0.f);
            acc[2] = fmaxf(acc[2] + b0.z, 0.f);
            acc[3] = fmaxf(acc[3] + b0.w, 0.f);
            acc[4] = fmaxf(acc[4] + b1.x, 0.f);
            acc[5] = fmaxf(acc[5] + b1.y, 0.f);
            acc[6] = fmaxf(acc[6] + b1.z, 0.f);
            acc[7] = fmaxf(acc[7] + b1.w, 0.f);
            *(uint4*)(Alds + lr * 272 + fl * 16) =
                make_uint4(pack_bf16(acc[0], acc[1]), pack_bf16(acc[2], acc[3]),
                           pack_bf16(acc[4], acc[5]), pack_bf16(acc[6], acc[7]));
        }
    }
    __syncthreads();

    // ---- phase 2: [64,128] @ [128,48] via MFMA; 4 waves x 16 rows ----
    const int w = t >> 6;
    const int l = t & 63;
    const int rl = l & 15;
    const int g = l >> 4;

    f32x4_t acc[3];
#pragma unroll
    for (int ct = 0; ct < 3; ++ct) acc[ct] = (f32x4_t){0.f, 0.f, 0.f, 0.f};

#pragma unroll
    for (int kc = 0; kc < 4; ++kc) {
        bf16x8_t a = *(const bf16x8_t*)(Alds + (w * 16 + rl) * 272 + kc * 64 + g * 16);
#pragma unroll
        for (int ct = 0; ct < 3; ++ct) {
            bf16x8_t b = *(const bf16x8_t*)(Wlds + (ct * 16 + rl) * 272 + kc * 64 + g * 16);
            acc[ct] = __builtin_amdgcn_mfma_f32_16x16x32_bf16(a, b, acc[ct], 0, 0, 0);
        }
    }
    __syncthreads();  // all Alds reads done; reuse as f32 bounce (pitch 52 f32)

    float* bounce = (float*)Alds;
#pragma unroll
    for (int ct = 0; ct < 3; ++ct)
#pragma unroll
        for (int r = 0; r < 4; ++r)
            bounce[(w * 16 + g * 4 + r) * 52 + ct * 16 + rl] = acc[ct][r];
    __syncthreads();

    for (int i = t; i < 1280; i += 256) {  // 64 rows x 20 u32
        int r = i / 20, j = i % 20;
        int row = row0 + r;
        if (row < n)
            C[(size_t)row * 20 + j] =
                pack_bf16(bounce[r * 52 + j * 2], bounce[r * 52 + j * 2 + 1]);
    }
}

// ------- agg40: out[n,40](f32) = sum X[csr[e],40](bf16) + bias ----------
// 8 lanes per node, lanes 0..4 each own a uint4; 32 nodes per block.

__global__ __launch_bounds__(256) void agg40_bf16(const unsigned* __restrict__ X,
                                                  const int* __restrict__ offsets,
                                                  const int* __restrict__ csr_src,
                                                  const float* __restrict__ bias,
                                                  float* __restrict__ Y, int n) {
    const int t = threadIdx.x;
    const int g = t >> 3;
    const int lane = t & 7;
    const int node = blockIdx.x * 32 + g;
    if (node >= n) return;
    const int e0 = offsets[node];
    const int e1 = offsets[node + 1];
    const bool active = lane < 5;
    const int cu = lane * 4;
    float acc[8] = {0.f, 0.f, 0.f, 0.f, 0.f, 0.f, 0.f, 0.f};
    int e = e0;
    for (; e + 3 < e1; e += 4) {
        int s0 = csr_src[e];
        int s1 = csr_src[e + 1];
        int s2 = csr_src[e + 2];
        int s3 = csr_src[e + 3];
        if (active) {
            uint4 v0 = *(const uint4*)(X + (size_t)s0 * 20 + cu);
            uint4 v1 = *(const uint4*)(X + (size_t)s1 * 20 + cu);
            uint4 v2 = *(const uint4*)(X + (size_t)s2 * 20 + cu);
            uint4 v3 = *(const uint4*)(X + (size_t)s3 * 20 + cu);
            bf16x8_add(acc, v0);
            bf16x8_add(acc, v1);
            bf16x8_add(acc, v2);
            bf16x8_add(acc, v3);
        }
    }
    for (; e < e1; ++e) {
        int s0 = csr_src[e];
        if (active) {
            uint4 v0 = *(const uint4*)(X + (size_t)s0 * 20 + cu);
            bf16x8_add(acc, v0);
        }
    }
    if (active) {
        float4 b0 = *(const float4*)(bias + lane * 8);
        float4 b1 = *(const float4*)(bias + lane * 8 + 4);
        float* yp = Y + (size_t)node * 40 + lane * 8;
        *(float4*)yp = make_float4(acc[0] + b0.x, acc[1] + b0.y,
                                   acc[2] + b0.z, acc[3] + b0.w);
        *(float4*)(yp + 4) = make_float4(acc[4] + b1.x, acc[5] + b1.y,
                                         acc[6] + b1.z, acc[7] + b1.w);
    }
}

// ---------------- launch ----------------

extern "C" void kernel_launch(void* const* d_in, const int* in_sizes, int n_in,
                              void* d_out, int out_size, void* d_ws, size_t ws_size,
                              hipStream_t stream) {
    const float* features = (const float*)d_in[0];
    const int* src = (const int*)d_in[1];
    const int* dst = (const int*)d_in[2];
    const float* W0 = (const float*)d_in[3];
    const float* b0 = (const float*)d_in[4];
    const float* W1 = (const float*)d_in[5];
    const float* b1 = (const float*)d_in[6];
    const float* W2 = (const float*)d_in[7];
    const float* b2 = (const float*)d_in[8];
    float* out = (float*)d_out;

    const int n_nodes = in_sizes[0] / FEAT;
    const int n_edges = in_sizes[1];
    const int nb = (n_nodes + 255) >> BIN_SHIFT;

    char* p = (char*)d_ws;
    auto alloc = [&](size_t bytes) {
        char* q = p;
        p += (bytes + 255) & ~(size_t)255;
        return q;
    };
    unsigned* bufA  = (unsigned*)alloc((size_t)n_nodes * FEAT * 2);  // bf16 [N,128]
    unsigned* bufB  = (unsigned*)alloc((size_t)n_nodes * FEAT * 2);  // bf16 [N,128]
    int* offsets    = (int*)alloc((size_t)(n_nodes + 1) * 4);
    int* csr        = (int*)alloc((size_t)n_edges * 4);
    int* ebuf       = (int*)alloc((size_t)n_edges * 4);
    int* bin_counts = (int*)alloc(MAX_BINS * 4);
    int* bin_offs   = (int*)alloc((MAX_BINS + 1) * 4);
    int* bin_cursor = (int*)alloc(MAX_BINS * 4);
    unsigned short* Wt0 = (unsigned short*)alloc(16384 * 2);
    unsigned short* Wt1 = (unsigned short*)alloc(16384 * 2);
    unsigned short* W2t = (unsigned short*)alloc(48 * 128 * 2);
    unsigned* bufC  = bufA;  // alias: bf16 [N,40] fits in bufA's region (bufA dead)

    // weight transpose (independent of CSR chain)
    prep_w<<<152, 256, 0, stream>>>(W0, W1, W2, Wt0, Wt1, W2t);

    // CSR build (binned)
    hipMemsetAsync(bin_counts, 0, MAX_BINS * 4, stream);
    bin_count<<<256, 256, 0, stream>>>(dst, bin_counts, n_edges, nb);
    bin_scan<<<1, 512, 0, stream>>>(bin_counts, bin_offs, bin_cursor, offsets,
                                    nb, n_nodes, n_edges);
    bin_scatter<<<(n_edges + SCAT_TILE - 1) / SCAT_TILE, 256, 0, stream>>>(
        src, dst, bin_cursor, ebuf, n_edges, nb);
    csr_build<<<nb, 256, 0, stream>>>(ebuf, bin_offs, offsets, csr, n_nodes);

    const int mmf_grid = (n_nodes + 127) / 128;
    const int fuse_grid = (n_nodes + 63) / 64;
    const int agg40_grid = (n_nodes + 31) / 32;

    // layer 0 matmul
    mm128_mfma<<<mmf_grid, 256, 0, stream>>>(features, (const unsigned*)Wt0, bufA, n_nodes);
    // layer 0 agg + layer 1 matmul (fused, MFMA)
    fused128<<<fuse_grid, 256, 0, stream>>>(bufA, offsets, csr, b0,
                                            (const unsigned*)Wt1, bufB, n_nodes);
    // layer 1 agg + layer 2 matmul (fused, MFMA)
    fused40<<<fuse_grid, 256, 0, stream>>>(bufB, offsets, csr, b1,
                                           (const unsigned*)W2t, bufC, n_nodes);
    // layer 2 agg + bias
    agg40_bf16<<<agg40_grid, 256, 0, stream>>>(bufC, offsets, csr, b2, out, n_nodes);
}

// Round 9
// 253.766 us; speedup vs baseline: 1.1847x; 1.0497x over previous
//
#include <hip/hip_runtime.h>
#include <hip/hip_bf16.h>

// GCN 3-layer. Linearity: segsum(h[src]) @ W == segsum((h@W)[src]).
// R9: DE-FUSE. R8 counters showed fused128 = 77.5us @ 32% occupancy vs the
//     unfused pair 57.6 (70% occ) + 15 = 72.6us. The gather is latency/L3-
//     bound and needs max resident waves; fusing an LDS-heavy MFMA phase +
//     barriers onto it halves occupancy. Keep every component in its
//     measured-best form:
//   CSR build (binned)   prep_w: Wt0/Wt1[128][128] + W2t[48][128] bf16
//   bufA = features @ Wt0        (mm128_mfma<f32 A>)
//   bufB = relu(agg(bufA)+b0)    (agg128_bf16, R5 shape: no LDS, 70% occ)
//   bufA = bufB @ Wt1            (mm128_mfma<bf16 A>)
//   bufB = relu(agg(bufA)+b1)    (agg128_bf16)
//   bufC = bufB @ W2t            (mm40_mfma)
//   out  = agg40(bufC) + b2      (agg40_bf16)

#define FEAT 128
#define BIN_SHIFT 8
#define MAX_BINS 512
#define SCAT_TILE 8192

typedef __attribute__((ext_vector_type(8))) short bf16x8_t;
typedef __attribute__((ext_vector_type(4))) float f32x4_t;

// ---------------- helpers ----------------

__device__ __forceinline__ void bf16x8_add(float* a, uint4 v) {
    a[0] += __uint_as_float(v.x << 16);
    a[1] += __uint_as_float(v.x & 0xffff0000u);
    a[2] += __uint_as_float(v.y << 16);
    a[3] += __uint_as_float(v.y & 0xffff0000u);
    a[4] += __uint_as_float(v.z << 16);
    a[5] += __uint_as_float(v.z & 0xffff0000u);
    a[6] += __uint_as_float(v.w << 16);
    a[7] += __uint_as_float(v.w & 0xffff0000u);
}

__device__ __forceinline__ unsigned pack_bf16(float a, float b) {
    union { __hip_bfloat162 h; unsigned u; } c;
    c.h.x = __float2bfloat16(a);
    c.h.y = __float2bfloat16(b);
    return c.u;
}

__device__ __forceinline__ unsigned short f2bf(float x) {
    union { __hip_bfloat16 h; unsigned short s; } c;
    c.h = __float2bfloat16(x);
    return c.s;
}

// ---------------- CSR build ----------------

__global__ __launch_bounds__(256) void bin_count(const int* __restrict__ dst,
                                                 int* __restrict__ bin_counts,
                                                 int n_edges, int nb) {
    __shared__ int hist[MAX_BINS];
    const int t = threadIdx.x;
    for (int i = t; i < nb; i += 256) hist[i] = 0;
    __syncthreads();
    const int n4 = n_edges >> 2;
    for (int i = blockIdx.x * 256 + t; i < n4; i += gridDim.x * 256) {
        int4 d = ((const int4*)dst)[i];
        atomicAdd(&hist[d.x >> BIN_SHIFT], 1);
        atomicAdd(&hist[d.y >> BIN_SHIFT], 1);
        atomicAdd(&hist[d.z >> BIN_SHIFT], 1);
        atomicAdd(&hist[d.w >> BIN_SHIFT], 1);
    }
    if (blockIdx.x == 0 && t < (n_edges & 3))
        atomicAdd(&hist[dst[n4 * 4 + t] >> BIN_SHIFT], 1);
    __syncthreads();
    for (int i = t; i < nb; i += 256) {
        int h = hist[i];
        if (h) atomicAdd(&bin_counts[i], h);
    }
}

__global__ __launch_bounds__(512) void bin_scan(const int* __restrict__ bin_counts,
                                                int* __restrict__ bin_offsets,
                                                int* __restrict__ bin_cursor,
                                                int* __restrict__ offsets,
                                                int nb, int n_nodes, int n_edges) {
    __shared__ int sc[512];
    const int t = threadIdx.x;
    const int v = (t < nb) ? bin_counts[t] : 0;
    sc[t] = v;
    __syncthreads();
    for (int off = 1; off < 512; off <<= 1) {
        int u = (t >= off) ? sc[t - off] : 0;
        __syncthreads();
        sc[t] += u;
        __syncthreads();
    }
    if (t <= nb) {
        int e = (t < nb) ? (sc[t] - v) : n_edges;
        bin_offsets[t] = e;
        if (t < nb) bin_cursor[t] = e;
    }
    if (t == 0) offsets[n_nodes] = n_edges;
}

__global__ __launch_bounds__(256) void bin_scatter(const int* __restrict__ src,
                                                   const int* __restrict__ dst,
                                                   int* __restrict__ bin_cursor,
                                                   int* __restrict__ ebuf,
                                                   int n_edges, int nb) {
    __shared__ int hist[MAX_BINS];
    __shared__ int cur[MAX_BINS];
    const int t = threadIdx.x;
    const int lo = blockIdx.x * SCAT_TILE;
    const int hi = min(lo + SCAT_TILE, n_edges);
    for (int i = t; i < nb; i += 256) hist[i] = 0;
    __syncthreads();
    for (int i = lo + t; i < hi; i += 256) atomicAdd(&hist[dst[i] >> BIN_SHIFT], 1);
    __syncthreads();
    for (int i = t; i < nb; i += 256) {
        int h = hist[i];
        cur[i] = h ? atomicAdd(&bin_cursor[i], h) : 0;
    }
    __syncthreads();
    for (int i = lo + t; i < hi; i += 256) {
        int d = dst[i];
        int b = d >> BIN_SHIFT;
        int pos = atomicAdd(&cur[b], 1);
        ebuf[pos] = ((d & 255) << 24) | src[i];
    }
}

__global__ __launch_bounds__(256) void csr_build(const int* __restrict__ ebuf,
                                                 const int* __restrict__ bin_offsets,
                                                 int* __restrict__ offsets,
                                                 int* __restrict__ csr,
                                                 int n_nodes) {
    __shared__ int cnt[256];
    __shared__ int sc[256];
    __shared__ int cur[256];
    const int b = blockIdx.x;
    const int t = threadIdx.x;
    const int lo = bin_offsets[b];
    const int hi = bin_offsets[b + 1];
    cnt[t] = 0;
    __syncthreads();
    for (int e = lo + t; e < hi; e += 256)
        atomicAdd(&cnt[((unsigned)ebuf[e]) >> 24], 1);
    __syncthreads();
    const int x = cnt[t];
    sc[t] = x;
    __syncthreads();
    for (int off = 1; off < 256; off <<= 1) {
        int u = (t >= off) ? sc[t - off] : 0;
        __syncthreads();
        sc[t] += u;
        __syncthreads();
    }
    const int start = lo + sc[t] - x;
    cur[t] = start;
    const int node = (b << BIN_SHIFT) + t;
    if (node < n_nodes) offsets[node] = start;
    __syncthreads();
    for (int e = lo + t; e < hi; e += 256) {
        int p = ebuf[e];
        int dl = ((unsigned)p) >> 24;
        int pos = atomicAdd(&cur[dl], 1);
        csr[pos] = p & 0x00FFFFFF;
    }
}

// -------- prep_w: Wt0/Wt1[n][k] bf16 from W0/W1[k][n] f32; W2t[48][128] bf16 ----

__global__ __launch_bounds__(256) void prep_w(const float* __restrict__ W0,
                                              const float* __restrict__ W1,
                                              const float* __restrict__ W2,
                                              unsigned short* __restrict__ Wt0,
                                              unsigned short* __restrict__ Wt1,
                                              unsigned short* __restrict__ W2t) {
    int i = blockIdx.x * 256 + threadIdx.x;  // 0..38911
    if (i < 32768) {
        const float* W = (i < 16384) ? W0 : W1;
        unsigned short* Wt = (i < 16384) ? Wt0 : Wt1;
        int ii = i & 16383;
        int k = ii >> 7, nn = ii & 127;
        Wt[nn * 128 + k] = f2bf(W[ii]);
    } else if (i < 32768 + 48 * 128) {
        int ii = i - 32768;           // nn*128 + k
        int nn = ii >> 7, k = ii & 127;
        W2t[ii] = (nn < 40) ? f2bf(W2[k * 40 + nn]) : (unsigned short)0;
    }
}

// ------- agg128_bf16: Y[n,128](bf16) = relu(sum_e X[csr[e],128](bf16) + bias) ----
// R5 shape: 16 lanes per node (uint4 = 8 bf16 each), 16 nodes per 256-thr block.
// No LDS, no barriers -> max occupancy for the latency-bound gather.

__global__ __launch_bounds__(256) void agg128_bf16(const unsigned* __restrict__ X,
                                                   const int* __restrict__ offsets,
                                                   const int* __restrict__ csr_src,
                                                   const float* __restrict__ bias,
                                                   unsigned* __restrict__ Yb, int n) {
    const int t = threadIdx.x;
    const int g = t >> 4;
    const int lane = t & 15;
    const int node = blockIdx.x * 16 + g;
    if (node >= n) return;
    const int e0 = offsets[node];
    const int e1 = offsets[node + 1];
    const int cu = lane * 4;
    float acc[8] = {0.f, 0.f, 0.f, 0.f, 0.f, 0.f, 0.f, 0.f};
    int e = e0;
    for (; e + 3 < e1; e += 4) {
        int s0 = csr_src[e];
        int s1 = csr_src[e + 1];
        int s2 = csr_src[e + 2];
        int s3 = csr_src[e + 3];
        uint4 v0 = *(const uint4*)(X + (size_t)s0 * 64 + cu);
        uint4 v1 = *(const uint4*)(X + (size_t)s1 * 64 + cu);
        uint4 v2 = *(const uint4*)(X + (size_t)s2 * 64 + cu);
        uint4 v3 = *(const uint4*)(X + (size_t)s3 * 64 + cu);
        bf16x8_add(acc, v0);
        bf16x8_add(acc, v1);
        bf16x8_add(acc, v2);
        bf16x8_add(acc, v3);
    }
    for (; e < e1; ++e) {
        int s0 = csr_src[e];
        uint4 v0 = *(const uint4*)(X + (size_t)s0 * 64 + cu);
        bf16x8_add(acc, v0);
    }
    float4 b0 = *(const float4*)(bias + lane * 8);
    float4 b1 = *(const float4*)(bias + lane * 8 + 4);
    acc[0] = fmaxf(acc[0] + b0.x, 0.f);
    acc[1] = fmaxf(acc[1] + b0.y, 0.f);
    acc[2] = fmaxf(acc[2] + b0.z, 0.f);
    acc[3] = fmaxf(acc[3] + b0.w, 0.f);
    acc[4] = fmaxf(acc[4] + b1.x, 0.f);
    acc[5] = fmaxf(acc[5] + b1.y, 0.f);
    acc[6] = fmaxf(acc[6] + b1.z, 0.f);
    acc[7] = fmaxf(acc[7] + b1.w, 0.f);
    *(uint4*)(Yb + (size_t)node * 64 + cu) =
        make_uint4(pack_bf16(acc[0], acc[1]), pack_bf16(acc[2], acc[3]),
                   pack_bf16(acc[4], acc[5]), pack_bf16(acc[6], acc[7]));
}

// ------- agg40_bf16: out[n,40](f32) = sum X[csr[e],40](bf16) + bias ----------
// 8 lanes per node, lanes 0..4 each own a uint4; 32 nodes per block.

__global__ __launch_bounds__(256) void agg40_bf16(const unsigned* __restrict__ X,
                                                  const int* __restrict__ offsets,
                                                  const int* __restrict__ csr_src,
                                                  const float* __restrict__ bias,
                                                  float* __restrict__ Y, int n) {
    const int t = threadIdx.x;
    const int g = t >> 3;
    const int lane = t & 7;
    const int node = blockIdx.x * 32 + g;
    if (node >= n) return;
    const int e0 = offsets[node];
    const int e1 = offsets[node + 1];
    const bool active = lane < 5;
    const int cu = lane * 4;
    float acc[8] = {0.f, 0.f, 0.f, 0.f, 0.f, 0.f, 0.f, 0.f};
    int e = e0;
    for (; e + 3 < e1; e += 4) {
        int s0 = csr_src[e];
        int s1 = csr_src[e + 1];
        int s2 = csr_src[e + 2];
        int s3 = csr_src[e + 3];
        if (active) {
            uint4 v0 = *(const uint4*)(X + (size_t)s0 * 20 + cu);
            uint4 v1 = *(const uint4*)(X + (size_t)s1 * 20 + cu);
            uint4 v2 = *(const uint4*)(X + (size_t)s2 * 20 + cu);
            uint4 v3 = *(const uint4*)(X + (size_t)s3 * 20 + cu);
            bf16x8_add(acc, v0);
            bf16x8_add(acc, v1);
            bf16x8_add(acc, v2);
            bf16x8_add(acc, v3);
        }
    }
    for (; e < e1; ++e) {
        int s0 = csr_src[e];
        if (active) {
            uint4 v0 = *(const uint4*)(X + (size_t)s0 * 20 + cu);
            bf16x8_add(acc, v0);
        }
    }
    if (active) {
        float4 b0 = *(const float4*)(bias + lane * 8);
        float4 b1 = *(const float4*)(bias + lane * 8 + 4);
        float* yp = Y + (size_t)node * 40 + lane * 8;
        *(float4*)yp = make_float4(acc[0] + b0.x, acc[1] + b0.y,
                                   acc[2] + b0.z, acc[3] + b0.w);
        *(float4*)(yp + 4) = make_float4(acc[4] + b1.x, acc[5] + b1.y,
                                         acc[6] + b1.z, acc[7] + b1.w);
    }
}

// ------- mm128_mfma: C[N,128](bf16) = A[N,128] @ Wt, MFMA 16x16x32 ----------
// 128 rows/block, 4 waves x 32 rows. AF32: A fp32 (features) vs bf16.

template <bool AF32>
__global__ __launch_bounds__(256) void mm128_mfma(const void* __restrict__ Av,
                                                  const unsigned* __restrict__ Wt,
                                                  unsigned* __restrict__ C, int n) {
    __shared__ __align__(16) unsigned char smem[128 * 272];  // W then C bounce
    const int t = threadIdx.x;
    const int w = t >> 6;
    const int l = t & 63;
    const int rl = l & 15;
    const int g = l >> 4;
    const int row0 = blockIdx.x * 128;

    for (int i = t; i < 2048; i += 256) {
        int nn = i >> 4, j = i & 15;
        *(uint4*)(smem + nn * 272 + j * 16) = *(const uint4*)(Wt + nn * 64 + j * 4);
    }

    bf16x8_t a[2][4];
#pragma unroll
    for (int rt = 0; rt < 2; ++rt) {
        const int row = row0 + w * 32 + rt * 16 + rl;
        const bool ok = row < n;
#pragma unroll
        for (int kc = 0; kc < 4; ++kc) {
            union { uint4 u; bf16x8_t h; } pk;
            pk.u = make_uint4(0, 0, 0, 0);
            if (AF32) {
                if (ok) {
                    const float* ap = (const float*)Av + (size_t)row * 128 + kc * 32 + g * 8;
                    float4 lo = *(const float4*)ap;
                    float4 hi = *(const float4*)(ap + 4);
                    pk.u = make_uint4(pack_bf16(lo.x, lo.y), pack_bf16(lo.z, lo.w),
                                      pack_bf16(hi.x, hi.y), pack_bf16(hi.z, hi.w));
                }
            } else {
                if (ok)
                    pk.u = *(const uint4*)((const unsigned*)Av + (size_t)row * 64 + kc * 16 + g * 4);
            }
            a[rt][kc] = pk.h;
        }
    }
    __syncthreads();

    f32x4_t acc[2][8];
#pragma unroll
    for (int rt = 0; rt < 2; ++rt)
#pragma unroll
        for (int ct = 0; ct < 8; ++ct)
            acc[rt][ct] = (f32x4_t){0.f, 0.f, 0.f, 0.f};

#pragma unroll
    for (int ct = 0; ct < 8; ++ct) {
#pragma unroll
        for (int kc = 0; kc < 4; ++kc) {
            bf16x8_t b = *(const bf16x8_t*)(smem + (ct * 16 + rl) * 272 + kc * 64 + g * 16);
            acc[0][ct] = __builtin_amdgcn_mfma_f32_16x16x32_bf16(a[0][kc], b, acc[0][ct], 0, 0, 0);
            acc[1][ct] = __builtin_amdgcn_mfma_f32_16x16x32_bf16(a[1][kc], b, acc[1][ct], 0, 0, 0);
        }
    }
    __syncthreads();

#pragma unroll
    for (int rt = 0; rt < 2; ++rt)
#pragma unroll
        for (int ct = 0; ct < 8; ++ct)
#pragma unroll
            for (int r = 0; r < 4; ++r) {
                int lr = w * 32 + rt * 16 + g * 4 + r;
                int col = ct * 16 + rl;
                *(unsigned short*)(smem + lr * 272 + col * 2) = f2bf(acc[rt][ct][r]);
            }
    __syncthreads();

    for (int i = t; i < 2048; i += 256) {
        int r = i >> 4, j = i & 15;
        int row = row0 + r;
        if (row < n)
            *(uint4*)(C + (size_t)row * 64 + j * 4) = *(const uint4*)(smem + r * 272 + j * 16);
    }
}

// ------- mm40_mfma: C[N,40](bf16) = A[N,128](bf16) @ W2t[48][128], MFMA ------
// 64 rows/block, 4 waves x 16 rows; A-frags direct from global; 12 MFMA/wave.

__global__ __launch_bounds__(256) void mm40_mfma(const unsigned* __restrict__ Ab,
                                                 const unsigned* __restrict__ W2t,
                                                 unsigned* __restrict__ C, int n) {
    __shared__ __align__(16) unsigned char Wlds[48 * 272];   // 13 KB
    __shared__ __align__(16) float bounce[64 * 52];          // 13.3 KB
    const int t = threadIdx.x;
    const int w = t >> 6;
    const int l = t & 63;
    const int rl = l & 15;
    const int g = l >> 4;
    const int row0 = blockIdx.x * 64;

    // stage W2t (48 rows x 16 uint4)
    for (int i = t; i < 768; i += 256) {
        int nn = i >> 4, j = i & 15;
        *(uint4*)(Wlds + nn * 272 + j * 16) = *(const uint4*)(W2t + nn * 64 + j * 4);
    }

    // A fragments from global
    bf16x8_t a[4];
    {
        const int row = row0 + w * 16 + rl;
        const bool ok = row < n;
#pragma unroll
        for (int kc = 0; kc < 4; ++kc) {
            union { uint4 u; bf16x8_t h; } pk;
            pk.u = make_uint4(0, 0, 0, 0);
            if (ok)
                pk.u = *(const uint4*)(Ab + (size_t)row * 64 + kc * 16 + g * 4);
            a[kc] = pk.h;
        }
    }
    __syncthreads();

    f32x4_t acc[3];
#pragma unroll
    for (int ct = 0; ct < 3; ++ct) acc[ct] = (f32x4_t){0.f, 0.f, 0.f, 0.f};

#pragma unroll
    for (int kc = 0; kc < 4; ++kc) {
#pragma unroll
        for (int ct = 0; ct < 3; ++ct) {
            bf16x8_t b = *(const bf16x8_t*)(Wlds + (ct * 16 + rl) * 272 + kc * 64 + g * 16);
            acc[ct] = __builtin_amdgcn_mfma_f32_16x16x32_bf16(a[kc], b, acc[ct], 0, 0, 0);
        }
    }

#pragma unroll
    for (int ct = 0; ct < 3; ++ct)
#pragma unroll
        for (int r = 0; r < 4; ++r)
            bounce[(w * 16 + g * 4 + r) * 52 + ct * 16 + rl] = acc[ct][r];
    __syncthreads();

    for (int i = t; i < 1280; i += 256) {  // 64 rows x 20 u32
        int r = i / 20, j = i % 20;
        int row = row0 + r;
        if (row < n)
            C[(size_t)row * 20 + j] =
                pack_bf16(bounce[r * 52 + j * 2], bounce[r * 52 + j * 2 + 1]);
    }
}

// ---------------- launch ----------------

extern "C" void kernel_launch(void* const* d_in, const int* in_sizes, int n_in,
                              void* d_out, int out_size, void* d_ws, size_t ws_size,
                              hipStream_t stream) {
    const float* features = (const float*)d_in[0];
    const int* src = (const int*)d_in[1];
    const int* dst = (const int*)d_in[2];
    const float* W0 = (const float*)d_in[3];
    const float* b0 = (const float*)d_in[4];
    const float* W1 = (const float*)d_in[5];
    const float* b1 = (const float*)d_in[6];
    const float* W2 = (const float*)d_in[7];
    const float* b2 = (const float*)d_in[8];
    float* out = (float*)d_out;

    const int n_nodes = in_sizes[0] / FEAT;
    const int n_edges = in_sizes[1];
    const int nb = (n_nodes + 255) >> BIN_SHIFT;

    char* p = (char*)d_ws;
    auto alloc = [&](size_t bytes) {
        char* q = p;
        p += (bytes + 255) & ~(size_t)255;
        return q;
    };
    unsigned* bufA  = (unsigned*)alloc((size_t)n_nodes * FEAT * 2);  // bf16 [N,128]
    unsigned* bufB  = (unsigned*)alloc((size_t)n_nodes * FEAT * 2);  // bf16 [N,128]
    int* offsets    = (int*)alloc((size_t)(n_nodes + 1) * 4);
    int* csr        = (int*)alloc((size_t)n_edges * 4);
    int* ebuf       = (int*)alloc((size_t)n_edges * 4);
    int* bin_counts = (int*)alloc(MAX_BINS * 4);
    int* bin_offs   = (int*)alloc((MAX_BINS + 1) * 4);
    int* bin_cursor = (int*)alloc(MAX_BINS * 4);
    unsigned short* Wt0 = (unsigned short*)alloc(16384 * 2);
    unsigned short* Wt1 = (unsigned short*)alloc(16384 * 2);
    unsigned short* W2t = (unsigned short*)alloc(48 * 128 * 2);
    unsigned* bufC  = bufA;  // alias: bf16 [N,40] fits in bufA's region (bufA dead)

    // weight transpose (independent of CSR chain)
    prep_w<<<152, 256, 0, stream>>>(W0, W1, W2, Wt0, Wt1, W2t);

    // CSR build (binned)
    hipMemsetAsync(bin_counts, 0, MAX_BINS * 4, stream);
    bin_count<<<256, 256, 0, stream>>>(dst, bin_counts, n_edges, nb);
    bin_scan<<<1, 512, 0, stream>>>(bin_counts, bin_offs, bin_cursor, offsets,
                                    nb, n_nodes, n_edges);
    bin_scatter<<<(n_edges + SCAT_TILE - 1) / SCAT_TILE, 256, 0, stream>>>(
        src, dst, bin_cursor, ebuf, n_edges, nb);
    csr_build<<<nb, 256, 0, stream>>>(ebuf, bin_offs, offsets, csr, n_nodes);

    const int mmf_grid = (n_nodes + 127) / 128;
    const int mm40_grid = (n_nodes + 63) / 64;
    const int agg_grid = (n_nodes + 15) / 16;
    const int agg40_grid = (n_nodes + 31) / 32;

    // layer 0
    mm128_mfma<true><<<mmf_grid, 256, 0, stream>>>(features, (const unsigned*)Wt0, bufA, n_nodes);
    agg128_bf16<<<agg_grid, 256, 0, stream>>>(bufA, offsets, csr, b0, bufB, n_nodes);
    // layer 1
    mm128_mfma<false><<<mmf_grid, 256, 0, stream>>>(bufB, (const unsigned*)Wt1, bufA, n_nodes);
    agg128_bf16<<<agg_grid, 256, 0, stream>>>(bufA, offsets, csr, b1, bufB, n_nodes);
    // layer 2: matmul-first (128->40), then aggregate + bias
    mm40_mfma<<<mm40_grid, 256, 0, stream>>>(bufB, (const unsigned*)W2t, bufC, n_nodes);
    agg40_bf16<<<agg40_grid, 256, 0, stream>>>(bufC, offsets, csr, b2, out, n_nodes);
}